// Round 13
// baseline (301.841 us; speedup 1.0000x reference)
//
#include <hip/hip_runtime.h>
#include <hip/hip_bf16.h>
#include <stdint.h>

// Problem constants
#define S2   2048
#define DD   4096
#define NH   32
#define NKVH 8
#define HD2  128
// qkv buffer row width: 4096 (q) + 1024 (k) + 1024 (v)
#define QKVW 6144

typedef __bf16 bf16x8 __attribute__((ext_vector_type(8)));
typedef float  f32x4  __attribute__((ext_vector_type(4)));
typedef unsigned short u16x8 __attribute__((ext_vector_type(8)));
typedef unsigned short u16x4 __attribute__((ext_vector_type(4)));

__device__ __forceinline__ unsigned short f2b(float f) {
    unsigned int u = __builtin_bit_cast(unsigned int, f);
    unsigned int r = (u + 0x7FFFu + ((u >> 16) & 1u)) >> 16;   // RNE
    return (unsigned short)r;
}
__device__ __forceinline__ float b2f(unsigned short h) {
    unsigned int u = ((unsigned int)h) << 16;
    return __builtin_bit_cast(float, u);
}
__device__ __forceinline__ unsigned cvt_pk_bf16(float a, float b) {
    unsigned r;
    asm("v_cvt_pk_bf16_f32 %0, %1, %2" : "=v"(r) : "v"(a), "v"(b));
    return r;   // lo16 = bf16(a), hi16 = bf16(b)
}

// global -> LDS direct copy, 16B per lane. LDS dest is wave-uniform base + lane*16.
__device__ __forceinline__ void gload_lds16(const void* g, void* lds) {
    __builtin_amdgcn_global_load_lds(
        (const __attribute__((address_space(1))) void*)(uintptr_t)g,
        (__attribute__((address_space(3))) void*)(uint32_t)(uintptr_t)lds,
        16, 0, 0);
}

// raw barrier (no vmcnt drain) + compiler memory fences so LDS ops don't cross
#define BAR() do { asm volatile("" ::: "memory"); \
                   __builtin_amdgcn_s_barrier();  \
                   asm volatile("" ::: "memory"); } while (0)
#define WAITV(n) asm volatile("s_waitcnt vmcnt(" #n ")" ::: "memory")

template<int N> __device__ __forceinline__ void waitv() {
    if      constexpr (N == 0)  WAITV(0);
    else if constexpr (N == 1)  WAITV(1);
    else if constexpr (N == 2)  WAITV(2);
    else if constexpr (N == 3)  WAITV(3);
    else if constexpr (N == 4)  WAITV(4);
    else if constexpr (N == 5)  WAITV(5);
    else if constexpr (N == 6)  WAITV(6);
    else if constexpr (N == 8)  WAITV(8);
}

// ---------------------------------------------------------------------------
// 1) fp32 -> bf16 conversion for x, wq, wk, wv, wo (concatenated into ws)
// ---------------------------------------------------------------------------
__global__ void cvt_all(const float* __restrict__ x,  const float* __restrict__ wq,
                        const float* __restrict__ wk, const float* __restrict__ wv,
                        const float* __restrict__ wo, unsigned short* __restrict__ dst) {
    const long long NG = 12LL * 1024 * 1024;  // float4 groups
    const long long stride = (long long)gridDim.x * blockDim.x;
    for (long long g = (long long)blockIdx.x * blockDim.x + threadIdx.x; g < NG; g += stride) {
        const float* src; long long off;
        if      (g < 2LL*1024*1024) { src = x;  off = g; }
        else if (g < 6LL*1024*1024) { src = wq; off = g - 2LL*1024*1024; }
        else if (g < 7LL*1024*1024) { src = wk; off = g - 6LL*1024*1024; }
        else if (g < 8LL*1024*1024) { src = wv; off = g - 7LL*1024*1024; }
        else                        { src = wo; off = g - 8LL*1024*1024; }
        f32x4 v = *reinterpret_cast<const f32x4*>(src + off * 4);
        u16x4 o;
        o[0] = f2b(v[0]); o[1] = f2b(v[1]); o[2] = f2b(v[2]); o[3] = f2b(v[3]);
        *reinterpret_cast<u16x4*>(dst + g * 4) = o;
    }
}

// ---------------------------------------------------------------------------
// 2) QKV GEMM  qkv[2048 x 6144] = x * [wq|wk|wv]^T.
//    r13: 768 threads = 12 waves (3/SIMD) as 4M x 3N, per-wave 64x64.
//    BM=256, BN=192, BK=64, grid (32,8) = 256 blocks. Same 8-phase skeleton.
//    Half h = rows {(r%64) < 32 xor h}: A-half = 16 8-row units, B-half = 12.
//    stageA: wave w stages unit w (w<12) + unit 12+(w&3) (dups same bytes,
//    proven trick) -> LA=2 uniform. stageB: unit w -> LB=1.
//    Ledger: prologue 3 | ph0 5 (2LA+LB) | ph1 4 (LA+2LB... = A0'+B0'+B1'=4) |
//    ph3 3 (B1'+A1') | peel 2/0.
// ---------------------------------------------------------------------------
__global__ __launch_bounds__(768) void gemm_qkv(
    const unsigned short* __restrict__ A,    // xb  [2048 x 4096]
    const unsigned short* __restrict__ B0,   // wq  [4096 x 4096]
    const unsigned short* __restrict__ B1,   // wk  [1024 x 4096]
    const unsigned short* __restrict__ B2,   // wv  [1024 x 4096]
    unsigned short* __restrict__ C)          // qkv [2048 x 6144]
{
    constexpr int K = 4096, BK = 64, NT = K / BK;
    __shared__ unsigned short As[2][256 * 64];   // 64 KB
    __shared__ unsigned short Bs[2][192 * 64];   // 48 KB

    const int bm = blockIdx.y, bn = blockIdx.x;  // (32, 8): lin%8 == bn%8
    const int tid = threadIdx.x;
    const int w = tid >> 6, lane = tid & 63;
    const int wr = w / 3, wc = w % 3;            // 4M x 3N
    const int r16 = lane & 15, g4 = lane >> 4;

    const int bn0 = bn * 192;
    const unsigned short* Ap = A + (size_t)bm * 256 * K;

    const int lrow = lane >> 3;   // 0..7 (row within 8-row unit)
    const int lchk = lane & 7;    // 0..7 (16B chunk within 128B row)

    f32x4 acc[4][4] = {};
    bf16x8 af[2][2], b0[2][2], b1[2][2];

    auto browbase = [&](int rowg) -> const unsigned short* {
        if (rowg < 4096) return B0 + (size_t)rowg * K;
        if (rowg < 5120) return B1 + (size_t)(rowg - 4096) * K;
        return B2 + (size_t)(rowg - 5120) * K;
    };

    // half h unit j: row0 = (j&3)*8 + (j>>2)*64 + h*32
    auto stageA = [&](int buf, int tt, int half) {
        #pragma unroll
        for (int i = 0; i < 2; ++i) {
            const int j = (i == 0) ? w : (12 + (w & 3));           // unit 0..15
            const int row0 = (j & 3) * 8 + (j >> 2) * 64 + half * 32;
            const int row = row0 + lrow;
            gload_lds16(Ap + (size_t)row * K + tt * BK + ((lchk ^ (row & 7)) * 8),
                        &As[buf][row0 * 64]);
        }
    };
    auto stageB = [&](int buf, int tt, int half) {
        const int j = w;                                           // unit 0..11
        const int row0 = (j & 3) * 8 + (j >> 2) * 64 + half * 32;
        const int row = row0 + lrow;
        const unsigned short* src = browbase(bn0 + row0) + (size_t)lrow * K;
        gload_lds16(src + tt * BK + ((lchk ^ (row & 7)) * 8),
                    &Bs[buf][row0 * 64]);
    };
    auto readA = [&](int buf, int mh) {
        #pragma unroll
        for (int m = 0; m < 2; ++m)
            #pragma unroll
            for (int kk = 0; kk < 2; ++kk) {
                const int row = wr * 64 + mh * 32 + m * 16 + r16;
                af[m][kk] = *reinterpret_cast<const bf16x8*>(
                    &As[buf][row * 64 + (((kk * 4 + g4) ^ (row & 7)) * 8)]);
            }
    };
    auto readB = [&](int buf, int nh, bf16x8 (&br)[2][2]) {
        #pragma unroll
        for (int n = 0; n < 2; ++n)
            #pragma unroll
            for (int kk = 0; kk < 2; ++kk) {
                const int row = wc * 64 + nh * 32 + n * 16 + r16;
                br[n][kk] = *reinterpret_cast<const bf16x8*>(
                    &Bs[buf][row * 64 + (((kk * 4 + g4) ^ (row & 7)) * 8)]);
            }
    };
    auto mma = [&](bf16x8 (&br)[2][2], int mh, int nh) {
        __builtin_amdgcn_s_setprio(1);
        #pragma unroll
        for (int m = 0; m < 2; ++m)
            #pragma unroll
            for (int n = 0; n < 2; ++n)
                #pragma unroll
                for (int kk = 0; kk < 2; ++kk)
                    acc[mh * 2 + m][nh * 2 + n] = __builtin_amdgcn_mfma_f32_16x16x32_bf16(
                        af[m][kk], br[n][kk], acc[mh * 2 + m][nh * 2 + n], 0, 0, 0);
        __builtin_amdgcn_s_setprio(0);
    };

    // prologue (issue order = consumption order A0 B0 B1 A1); leave B1+A1 = 3
    stageA(0, 0, 0); stageB(0, 0, 0); stageB(0, 0, 1); stageA(0, 0, 1);
    waitv<3>();
    BAR();

    for (int t = 0; t < NT - 1; ++t) {
        const int buf = t & 1;
        // ---- phase 0: Q(0,0) ----
        readA(buf, 0); readB(buf, 0, b0);
        stageA(buf ^ 1, t + 1, 0); stageB(buf ^ 1, t + 1, 0);
        BAR();
        mma(b0, 0, 0);
        waitv<5>();                 // need B-h1(t); newer: A1(t)2 + A0'(2) + B0'(1)
        BAR();
        // ---- phase 1: Q(0,1) ----
        readB(buf, 1, b1);
        stageB(buf ^ 1, t + 1, 1);
        BAR();
        mma(b1, 0, 1);
        waitv<4>();                 // need A-h1(t); newer: A0'(2) + B0'(1) + B1'(1)
        BAR();
        // ---- phase 2: Q(1,1) ----
        readA(buf, 1);
        stageA(buf ^ 1, t + 1, 1);
        BAR();
        mma(b1, 1, 1);
        BAR();
        // ---- phase 3: Q(1,0) ----
        mma(b0, 1, 0);
        waitv<3>();                 // need A-h0(t+1), B-h0(t+1); newer: B1'(1)+A1'(2)
        BAR();
    }
    // ---- last tile (no staging; peeled vmcnt) ----
    {
        const int buf = (NT - 1) & 1;
        readA(buf, 0); readB(buf, 0, b0);
        BAR();
        mma(b0, 0, 0);
        waitv<2>();                 // need B-h1; newer: A-h1 (LA=2)
        BAR();
        readB(buf, 1, b1);
        mma(b1, 0, 1);
        waitv<0>();
        readA(buf, 1);
        mma(b1, 1, 1);
        mma(b0, 1, 0);
    }

    // ---- epilogue ----
    const size_t crow0 = (size_t)bm * 256 + wr * 64;
    const size_t ccol0 = (size_t)bn0 + wc * 64;
    #pragma unroll
    for (int mh = 0; mh < 2; ++mh)
        #pragma unroll
        for (int m = 0; m < 2; ++m)
            #pragma unroll
            for (int nh = 0; nh < 2; ++nh)
                #pragma unroll
                for (int n = 0; n < 2; ++n)
                    #pragma unroll
                    for (int r = 0; r < 4; ++r) {
                        const size_t row = crow0 + mh * 32 + m * 16 + g4 * 4 + r;
                        const size_t col = ccol0 + nh * 32 + n * 16 + r16;
                        C[row * QKVW + col] = f2b(acc[mh * 2 + m][nh * 2 + n][r]);
                    }
}

// ---------------------------------------------------------------------------
// 2b) O-proj GEMM  out[2048 x 4096] = ob * wo^T.  (unchanged from r9)
//     BM=128, BN=256, BK=64 -> grid (16,16) = 256 blocks. 8 waves 2M x 4N.
// ---------------------------------------------------------------------------
__global__ __launch_bounds__(512) void gemm_out(
    const unsigned short* __restrict__ A,   // ob  [2048 x 4096] bf16
    const unsigned short* __restrict__ B,   // wob [4096 x 4096] bf16
    float* __restrict__ C)                  // out [2048 x 4096] f32
{
    constexpr int K = 4096, BK = 64, NT = K / BK;
    __shared__ unsigned short As[2][128 * 64];   // 32 KB
    __shared__ unsigned short Bs[2][256 * 64];   // 64 KB

    const int bm = blockIdx.y, bn = blockIdx.x;  // (16, 16): lin%8 == bn%8
    const int tid = threadIdx.x;
    const int w = tid >> 6, lane = tid & 63;
    const int wr = w >> 2, wc = w & 3;           // 2M x 4N
    const int r16 = lane & 15, g4 = lane >> 4;

    const unsigned short* Ap = A + (size_t)bm * 128 * K;
    const unsigned short* Bp = B + (size_t)bn * 256 * K;

    const int lrow = lane >> 3;
    const int lchk = lane & 7;

    f32x4 acc[4][4] = {};
    bf16x8 af[2][2], b0[2][2], b1[2][2];

    auto stageA = [&](int buf, int tt, int half) {
        const int j = w;                                           // unit 0..7
        const int row0 = (j >> 2) * 64 + half * 32 + (j & 3) * 8;
        const int row = row0 + lrow;
        gload_lds16(Ap + (size_t)row * K + tt * BK + ((lchk ^ (row & 7)) * 8),
                    &As[buf][row0 * 64]);
    };
    auto stageB = [&](int buf, int tt, int half) {
        #pragma unroll
        for (int i = 0; i < 2; ++i) {
            const int j = i * 8 + w;                               // unit 0..15
            const int row0 = (j >> 2) * 64 + half * 32 + (j & 3) * 8;
            const int row = row0 + lrow;
            gload_lds16(Bp + (size_t)row * K + tt * BK + ((lchk ^ (row & 7)) * 8),
                        &Bs[buf][row0 * 64]);
        }
    };
    auto readA = [&](int buf, int mh) {
        #pragma unroll
        for (int m = 0; m < 2; ++m)
            #pragma unroll
            for (int kk = 0; kk < 2; ++kk) {
                const int row = wr * 64 + mh * 32 + m * 16 + r16;
                af[m][kk] = *reinterpret_cast<const bf16x8*>(
                    &As[buf][row * 64 + (((kk * 4 + g4) ^ (row & 7)) * 8)]);
            }
    };
    auto readB = [&](int buf, int nh, bf16x8 (&br)[2][2]) {
        #pragma unroll
        for (int n = 0; n < 2; ++n)
            #pragma unroll
            for (int kk = 0; kk < 2; ++kk) {
                const int row = wc * 64 + nh * 32 + n * 16 + r16;
                br[n][kk] = *reinterpret_cast<const bf16x8*>(
                    &Bs[buf][row * 64 + (((kk * 4 + g4) ^ (row & 7)) * 8)]);
            }
    };
    auto mma = [&](bf16x8 (&br)[2][2], int mh, int nh) {
        __builtin_amdgcn_s_setprio(1);
        #pragma unroll
        for (int m = 0; m < 2; ++m)
            #pragma unroll
            for (int n = 0; n < 2; ++n)
                #pragma unroll
                for (int kk = 0; kk < 2; ++kk)
                    acc[mh * 2 + m][nh * 2 + n] = __builtin_amdgcn_mfma_f32_16x16x32_bf16(
                        af[m][kk], br[n][kk], acc[mh * 2 + m][nh * 2 + n], 0, 0, 0);
        __builtin_amdgcn_s_setprio(0);
    };

    stageA(0, 0, 0); stageB(0, 0, 0); stageB(0, 0, 1); stageA(0, 0, 1);
    waitv<3>();                     // LA+LB
    BAR();

    for (int t = 0; t < NT - 1; ++t) {
        const int buf = t & 1;
        readA(buf, 0); readB(buf, 0, b0);
        stageA(buf ^ 1, t + 1, 0); stageB(buf ^ 1, t + 1, 0);
        BAR();
        mma(b0, 0, 0);
        waitv<4>();                 // 2LA+LB
        BAR();
        readB(buf, 1, b1);
        stageB(buf ^ 1, t + 1, 1);
        BAR();
        mma(b1, 0, 1);
        waitv<5>();                 // LA+2LB
        BAR();
        readA(buf, 1);
        stageA(buf ^ 1, t + 1, 1);
        BAR();
        mma(b1, 1, 1);
        BAR();
        mma(b0, 1, 0);
        waitv<3>();                 // LA+LB
        BAR();
    }
    {
        const int buf = (NT - 1) & 1;
        readA(buf, 0); readB(buf, 0, b0);
        BAR();
        mma(b0, 0, 0);
        waitv<1>();
        BAR();
        readB(buf, 1, b1);
        mma(b1, 0, 1);
        waitv<0>();
        readA(buf, 1);
        mma(b1, 1, 1);
        mma(b0, 1, 0);
    }

    const size_t crow0 = (size_t)bm * 128 + wr * 64;
    const size_t ccol0 = (size_t)bn * 256 + wc * 64;
    #pragma unroll
    for (int m = 0; m < 4; ++m)
        #pragma unroll
        for (int n = 0; n < 4; ++n)
            #pragma unroll
            for (int r = 0; r < 4; ++r)
                C[(crow0 + m * 16 + g4 * 4 + r) * DD + ccol0 + n * 16 + r16] = acc[m][n][r];
}

// ---------------------------------------------------------------------------
// 3) RoPE in-place on q/k cols of qkv. Q part scaled by log2(e)/sqrt(HD).
// ---------------------------------------------------------------------------
__global__ __launch_bounds__(256) void rope_kernel(unsigned short* __restrict__ qkv,
                                                   const float* __restrict__ fc,
                                                   const float* __restrict__ fs) {
    constexpr float QSCALE = 0.08838834764831845f * 1.4426950408889634f; // 1/sqrt(128)*log2(e)
    const int g = blockIdx.x * 256 + threadIdx.x;     // 0..767, groups of 8 cols
    if (g >= 640) return;
    const int s = blockIdx.y;
    const int col = g * 8;                            // within first 5120 cols
    unsigned short* p = qkv + (size_t)s * QKVW + col;
    u16x8 v = *reinterpret_cast<const u16x8*>(p);
    const int i0 = (col & 127) >> 1;
    f32x4 c  = *reinterpret_cast<const f32x4*>(fc + s * 64 + i0);
    f32x4 sn = *reinterpret_cast<const f32x4*>(fs + s * 64 + i0);
    const float post = (col < DD) ? QSCALE : 1.0f;
    u16x8 o;
    #pragma unroll
    for (int j = 0; j < 4; ++j) {
        float e  = b2f(v[2*j]);
        float od = b2f(v[2*j+1]);
        o[2*j]   = f2b((e * c[j] - od * sn[j]) * post);
        o[2*j+1] = f2b((e * sn[j] + od * c[j]) * post);
    }
    *reinterpret_cast<u16x8*>(p) = o;
}

// ---------------------------------------------------------------------------
// 4) Transpose V part of qkv (cols 5120..6144) into Vt[kvh][128][S2]
// ---------------------------------------------------------------------------
__global__ __launch_bounds__(256) void transpose_v(const unsigned short* __restrict__ qkv,
                                                   unsigned short* __restrict__ Vt) {
    __shared__ unsigned short tile[64][72];
    const int d0g = blockIdx.x * 64;
    const int s0  = blockIdx.y * 64;
    const int kvh = d0g >> 7, dl0 = d0g & 127;
    const int tid = threadIdx.x;
    #pragma unroll
    for (int p = 0; p < 2; ++p) {
        const int sgi = p * 256 + tid;
        const int srow = sgi >> 3, dseg = sgi & 7;
        u16x8 v = *reinterpret_cast<const u16x8*>(
            qkv + (size_t)(s0 + srow) * QKVW + 5120 + d0g + dseg * 8);
        #pragma unroll
        for (int j = 0; j < 8; ++j) tile[srow][dseg * 8 + j] = v[j];
    }
    __syncthreads();
    #pragma unroll
    for (int p = 0; p < 2; ++p) {
        const int sgi = p * 256 + tid;
        const int drow = sgi >> 3, sseg = sgi & 7;
        u16x8 v;
        #pragma unroll
        for (int j = 0; j < 8; ++j) v[j] = tile[sseg * 8 + j][drow];
        *reinterpret_cast<u16x8*>(
            Vt + (size_t)kvh * HD2 * S2 + (size_t)(dl0 + drow) * S2 + s0 + sseg * 8) = v;
    }
}

// ---------------------------------------------------------------------------
// 5) Flash attention v8: r12 complement-pair structure + ring-3 K/V staging
//    with counted vmcnt (T3/T4). Stage tile t+2 during tile t; end-of-tile
//    WAITV(4) (leave stage(t+2)'s 4 loads in flight) instead of drain-0.
//    Slot safety: write slot (t+2)%3 == (t-1)%3, freed at t-1's end barrier;
//    issue happens after it. LDS = 48K K + 48V + 32P = 128 KB (1 block/CU,
//    unchanged). Per-tile body identical to r12.
// ---------------------------------------------------------------------------
__global__ __launch_bounds__(512) void attn_kernel(const unsigned short* __restrict__ Qkv,
                                                   const unsigned short* __restrict__ Vt,
                                                   unsigned short* __restrict__ O) {
    __shared__ unsigned short Klds[3][64 * 128];   // 48 KB
    __shared__ unsigned short Vlds[3][128 * 64];   // 48 KB
    __shared__ unsigned short Plds[8][2048];       // 32 KB (4 KB/wave, frag-ordered)

    const int kvh = blockIdx.x;                  // 0..7
    const int h   = kvh * 4 + (blockIdx.y & 3);
    const int p   = blockIdx.y >> 2;             // pair id 0..7
    const int cB  = 8 + p, cS = 7 - p;           // complement chunks
    const int w = threadIdx.x >> 6, lane = threadIdx.x & 63;
    const int r16 = lane & 15, g4 = lane >> 4;

    const int myc = (w < 4) ? cB : cS;
    const int qw  = myc * 128 + (w & 3) * 32;    // wave's first q row
    const int ntB = 2 * cB + 2;                  // tiles staged by this block (>= 18)

    const unsigned short* Kbase = Qkv + DD + kvh * HD2;      // + kv*QKVW + d
    const unsigned short* Vtb   = Vt + (size_t)kvh * HD2 * S2;
    char* pw = (char*)(&Plds[w][0]);             // wave's 4KB P region

    // staging lane constants
    const int krow_l = lane >> 4;      // row within 4-row segment
    const int kchunk = lane & 15;      // 16B chunk within 256B K row
    const int vd_l   = lane >> 3;      // d within 8-row segment
    const int vchunk = lane & 7;       // 16B chunk within 128B V row

    // Q fragments (B-frag of swapped QK^T): rows qw+m*16+r16, d-slices f*32+g4*8
    bf16x8 qf[2][4];
    #pragma unroll
    for (int m = 0; m < 2; ++m)
        #pragma unroll
        for (int f = 0; f < 4; ++f)
            qf[m][f] = *reinterpret_cast<const bf16x8*>(
                Qkv + (size_t)(qw + m * 16 + r16) * QKVW + h * HD2 + f * 32 + g4 * 8);

    f32x4 o[2][8] = {};
    float mr[2] = {-3e38f, -3e38f};   // running max (log2 units) for q = m*16+r16
    float lr[2] = {0.f, 0.f};

    auto stage = [&](int slot, int kv0) {        // 4 loads/wave (2 K + 2 V)
        #pragma unroll
        for (int i = 0; i < 2; ++i) {
            const int seg = i * 8 + w;                     // 0..15
            const int row = seg * 4 + krow_l;              // kv row 0..63
            gload_lds16(Kbase + (size_t)(kv0 + row) * QKVW + ((kchunk ^ (row & 7)) * 8),
                        &Klds[slot][seg * 512]);
        }
        #pragma unroll
        for (int i = 0; i < 2; ++i) {
            const int seg = i * 8 + w;
            const int d = seg * 8 + vd_l;                  // d row 0..127
            gload_lds16(Vtb + (size_t)d * S2 + kv0 + ((vchunk ^ (d & 7)) * 8),
                        &Vlds[slot][seg * 512]);
        }
    };

    // prologue: stage tiles 0,1; wait tile 0 (leave tile 1's 4 in flight)
    stage(0, 0);
    stage(1, 64);
    WAITV(4);
    __syncthreads();

    int rs = 0, ws2 = 2;                          // read slot, write slot
    for (int t = 0; t < ntB; ++t) {
        const int kv0 = t * 64;
        if (t + 2 < ntB) stage(ws2, (t + 2) * 64);

        if (kv0 <= qw + 31) {                 // causal: this wave needs the tile
            // ---- QK^T swapped: sa[m][kb] = K_tile * Q^T -> C[kv][q] ----
            f32x4 sa[2][4] = {};
            #pragma unroll
            for (int kb = 0; kb < 4; ++kb) {
                bf16x8 kf[4];
                #pragma unroll
                for (int f = 0; f < 4; ++f)
                    kf[f] = *reinterpret_cast<const bf16x8*>(
                        &Klds[rs][(kb * 16 + r16) * 128 + (((f * 4 + g4) ^ (r16 & 7)) * 8)]);
                __builtin_amdgcn_s_setprio(1);
                #pragma unroll
                for (int m = 0; m < 2; ++m)
                    #pragma unroll
                    for (int f = 0; f < 4; ++f)
                        sa[m][kb] = __builtin_amdgcn_mfma_f32_16x16x32_bf16(
                            kf[f], qf[m][f], sa[m][kb], 0, 0, 0);
                __builtin_amdgcn_s_setprio(0);
            }
            // ---- causal mask: lane holds q = qw+m*16+r16, kv = kv0+kb*16+g4*4+r ----
            const bool needmask = (kv0 + 63 > qw);
            float sv[2][4][4];
            #pragma unroll
            for (int m = 0; m < 2; ++m)
                #pragma unroll
                for (int kb = 0; kb < 4; ++kb)
                    #pragma unroll
                    for (int r = 0; r < 4; ++r) {
                        float xx = sa[m][kb][r];
                        if (needmask) {
                            const int kvg = kv0 + kb * 16 + g4 * 4 + r;
                            const int qg  = qw + m * 16 + r16;
                            xx = (kvg > qg) ? -3e38f : xx;
                        }
                        sv[m][kb][r] = xx;
                    }
            // ---- per-q max: 15 in-lane ops + 2 shfl levels ----
            float rowm[2];
            #pragma unroll
            for (int m = 0; m < 2; ++m) {
                float a0 = fmaxf(fmaxf(sv[m][0][0], sv[m][0][1]), fmaxf(sv[m][0][2], sv[m][0][3]));
                float a1 = fmaxf(fmaxf(sv[m][1][0], sv[m][1][1]), fmaxf(sv[m][1][2], sv[m][1][3]));
                float a2 = fmaxf(fmaxf(sv[m][2][0], sv[m][2][1]), fmaxf(sv[m][2][2], sv[m][2][3]));
                float a3 = fmaxf(fmaxf(sv[m][3][0], sv[m][3][1]), fmaxf(sv[m][3][2], sv[m][3][3]));
                rowm[m] = fmaxf(fmaxf(a0, a1), fmaxf(a2, a3));
            }
            #pragma unroll
            for (int m = 0; m < 2; ++m) {
                rowm[m] = fmaxf(rowm[m], __shfl_xor(rowm[m], 16));
                rowm[m] = fmaxf(rowm[m], __shfl_xor(rowm[m], 32));
            }
            // ---- defer-max (T13, base-2 THR = 11.5 ~ e^8) ----
            const float gmax = fmaxf(rowm[0] - mr[0], rowm[1] - mr[1]);
            if (!__all(gmax <= 11.5f)) {
                float corr[2];
                #pragma unroll
                for (int m = 0; m < 2; ++m) {
                    const float mn = fmaxf(mr[m], rowm[m]);
                    corr[m] = exp2f(mr[m] - mn);
                    mr[m] = mn;
                    lr[m] *= corr[m];
                }
                #pragma unroll
                for (int m = 0; m < 2; ++m)
                    #pragma unroll
                    for (int r = 0; r < 4; ++r) {
                        const float co = __shfl(corr[m], (lane & 48) | (g4 * 4 + r));
                        #pragma unroll
                        for (int n = 0; n < 8; ++n) o[m][n][r] *= co;
                    }
            }
            // ---- P = exp2(S - m), row sums (in-lane + 2 shfl) ----
            float rsum[2] = {0.f, 0.f};
            #pragma unroll
            for (int m = 0; m < 2; ++m)
                #pragma unroll
                for (int kb = 0; kb < 4; ++kb)
                    #pragma unroll
                    for (int r = 0; r < 4; ++r) {
                        const float pp = exp2f(sv[m][kb][r] - mr[m]);
                        sv[m][kb][r] = pp;
                        rsum[m] += pp;
                    }
            #pragma unroll
            for (int m = 0; m < 2; ++m) {
                rsum[m] += __shfl_xor(rsum[m], 16);
                rsum[m] += __shfl_xor(rsum[m], 32);
                lr[m] += rsum[m];
            }
            // ---- pack P pairs (cvt_pk) -> fragment-ordered Plds, 8 b64 writes ----
            #pragma unroll
            for (int m = 0; m < 2; ++m)
                #pragma unroll
                for (int kb = 0; kb < 4; ++kb) {
                    const unsigned w0 = cvt_pk_bf16(sv[m][kb][0], sv[m][kb][1]);
                    const unsigned w1 = cvt_pk_bf16(sv[m][kb][2], sv[m][kb][3]);
                    int wa = m * 2048 + ((kb * 2) + (g4 >> 1)) * 256 + r16 * 16 + (g4 & 1) * 8;
                    wa ^= (r16 >> 3) << 4;
                    *reinterpret_cast<unsigned long long*>(pw + wa) =
                        (unsigned long long)w0 | ((unsigned long long)w1 << 32);
                }
            asm volatile("s_waitcnt lgkmcnt(0)" ::: "memory");
            bf16x8 pa[2][2];
            #pragma unroll
            for (int m = 0; m < 2; ++m)
                #pragma unroll
                for (int kvs = 0; kvs < 2; ++kvs) {
                    int ra = m * 2048 + kvs * 1024 + lane * 16;
                    ra ^= (r16 >> 3) << 4;
                    pa[m][kvs] = *reinterpret_cast<const bf16x8*>(pw + ra);
                }
            // ---- PV: O[q][d] += P[q][kv] * Vt[d][kv] ----
            #pragma unroll
            for (int kvs = 0; kvs < 2; ++kvs)
                #pragma unroll
                for (int n = 0; n < 8; ++n) {
                    const bf16x8 vb = *reinterpret_cast<const bf16x8*>(
                        &Vlds[rs][(n * 16 + r16) * 64 + (((kvs * 4 + g4) ^ (r16 & 7)) * 8)]);
                    __builtin_amdgcn_s_setprio(1);
                    #pragma unroll
                    for (int m = 0; m < 2; ++m)
                        o[m][n] = __builtin_amdgcn_mfma_f32_16x16x32_bf16(
                            pa[m][kvs], vb, o[m][n], 0, 0, 0);
                    __builtin_amdgcn_s_setprio(0);
                }
        }

        if (t + 2 < ntB) { WAITV(4); } else { WAITV(0); }   // tile t+1 landed
        __syncthreads();
        rs  = (rs  == 2) ? 0 : rs  + 1;
        ws2 = (ws2 == 2) ? 0 : ws2 + 1;
    }

    // ---- normalize (broadcast 1/lr to o-layout lanes) + write ----
    float inv[2];
    #pragma unroll
    for (int m = 0; m < 2; ++m) inv[m] = 1.0f / lr[m];
    #pragma unroll
    for (int m = 0; m < 2; ++m)
        #pragma unroll
        for (int r = 0; r < 4; ++r) {
            const float iv = __shfl(inv[m], (lane & 48) | (g4 * 4 + r));
            #pragma unroll
            for (int n = 0; n < 8; ++n)
                O[(size_t)(qw + m * 16 + g4 * 4 + r) * DD + h * HD2 + n * 16 + r16] =
                    f2b(o[m][n][r] * iv);
        }
}

// ---------------------------------------------------------------------------
extern "C" void kernel_launch(void* const* d_in, const int* in_sizes, int n_in,
                              void* d_out, int out_size, void* d_ws, size_t ws_size,
                              hipStream_t stream) {
    (void)in_sizes; (void)n_in; (void)out_size; (void)ws_size;
    const float* x  = (const float*)d_in[0];
    const float* wq = (const float*)d_in[1];
    const float* wk = (const float*)d_in[2];
    const float* wv = (const float*)d_in[3];
    const float* wo = (const float*)d_in[4];
    // d_in[5] = mask (causal tril; computed analytically in-kernel)
    const float* fc = (const float*)d_in[6];
    const float* fs = (const float*)d_in[7];
    float* out = (float*)d_out;

    unsigned short* ws = (unsigned short*)d_ws;
    const size_t M1 = 1024 * 1024;
    unsigned short* xb  = ws;              // 8M  (x bf16)
    unsigned short* wqb = ws + 8  * M1;    // 16M
    unsigned short* wkb = ws + 24 * M1;    // 4M
    unsigned short* wvb = ws + 28 * M1;    // 4M
    unsigned short* wob = ws + 32 * M1;    // 16M
    unsigned short* qkv = ws + 48 * M1;    // 12M (S x 6144)
    unsigned short* vt  = ws + 60 * M1;    // 2M  (KVH x 128 x S)
    unsigned short* ob  = ws + 62 * M1;    // 8M  (S x 4096)

    cvt_all<<<2048, 256, 0, stream>>>(x, wq, wk, wv, wo, ws);
    gemm_qkv<<<dim3(32, 8), 768, 0, stream>>>(xb, wqb, wkb, wvb, qkv);
    rope_kernel<<<dim3(3, 2048), 256, 0, stream>>>(qkv, fc, fs);
    transpose_v<<<dim3(16, 32), 256, 0, stream>>>(qkv, vt);
    attn_kernel<<<dim3(8, 32), 512, 0, stream>>>(qkv, vt, ob);
    gemm_out<<<dim3(16, 16), 512, 0, stream>>>(ob, wob, out);
}

// Round 14
// 300.538 us; speedup vs baseline: 1.0043x; 1.0043x over previous
//
#include <hip/hip_runtime.h>
#include <hip/hip_bf16.h>
#include <stdint.h>

// Problem constants
#define S2   2048
#define DD   4096
#define NH   32
#define NKVH 8
#define HD2  128
// qkv buffer row width: 4096 (q) + 1024 (k) + 1024 (v)
#define QKVW 6144

typedef __bf16 bf16x8 __attribute__((ext_vector_type(8)));
typedef float  f32x4  __attribute__((ext_vector_type(4)));
typedef unsigned short u16x8 __attribute__((ext_vector_type(8)));
typedef unsigned short u16x4 __attribute__((ext_vector_type(4)));

__device__ __forceinline__ unsigned short f2b(float f) {
    unsigned int u = __builtin_bit_cast(unsigned int, f);
    unsigned int r = (u + 0x7FFFu + ((u >> 16) & 1u)) >> 16;   // RNE
    return (unsigned short)r;
}
__device__ __forceinline__ float b2f(unsigned short h) {
    unsigned int u = ((unsigned int)h) << 16;
    return __builtin_bit_cast(float, u);
}
__device__ __forceinline__ unsigned cvt_pk_bf16(float a, float b) {
    unsigned r;
    asm("v_cvt_pk_bf16_f32 %0, %1, %2" : "=v"(r) : "v"(a), "v"(b));
    return r;   // lo16 = bf16(a), hi16 = bf16(b)
}

// global -> LDS direct copy, 16B per lane. LDS dest is wave-uniform base + lane*16.
__device__ __forceinline__ void gload_lds16(const void* g, void* lds) {
    __builtin_amdgcn_global_load_lds(
        (const __attribute__((address_space(1))) void*)(uintptr_t)g,
        (__attribute__((address_space(3))) void*)(uint32_t)(uintptr_t)lds,
        16, 0, 0);
}

// raw barrier (no vmcnt drain) + compiler memory fences so LDS ops don't cross
#define BAR() do { asm volatile("" ::: "memory"); \
                   __builtin_amdgcn_s_barrier();  \
                   asm volatile("" ::: "memory"); } while (0)
#define WAITV(n) asm volatile("s_waitcnt vmcnt(" #n ")" ::: "memory")

template<int N> __device__ __forceinline__ void waitv() {
    if      constexpr (N == 0)  WAITV(0);
    else if constexpr (N == 1)  WAITV(1);
    else if constexpr (N == 2)  WAITV(2);
    else if constexpr (N == 3)  WAITV(3);
    else if constexpr (N == 4)  WAITV(4);
    else if constexpr (N == 5)  WAITV(5);
    else if constexpr (N == 6)  WAITV(6);
    else if constexpr (N == 8)  WAITV(8);
}

// ---------------------------------------------------------------------------
// 1) fp32 -> bf16 conversion for x, wq, wk, wv, wo (concatenated into ws)
// ---------------------------------------------------------------------------
__global__ void cvt_all(const float* __restrict__ x,  const float* __restrict__ wq,
                        const float* __restrict__ wk, const float* __restrict__ wv,
                        const float* __restrict__ wo, unsigned short* __restrict__ dst) {
    const long long NG = 12LL * 1024 * 1024;  // float4 groups
    const long long stride = (long long)gridDim.x * blockDim.x;
    for (long long g = (long long)blockIdx.x * blockDim.x + threadIdx.x; g < NG; g += stride) {
        const float* src; long long off;
        if      (g < 2LL*1024*1024) { src = x;  off = g; }
        else if (g < 6LL*1024*1024) { src = wq; off = g - 2LL*1024*1024; }
        else if (g < 7LL*1024*1024) { src = wk; off = g - 6LL*1024*1024; }
        else if (g < 8LL*1024*1024) { src = wv; off = g - 7LL*1024*1024; }
        else                        { src = wo; off = g - 8LL*1024*1024; }
        f32x4 v = *reinterpret_cast<const f32x4*>(src + off * 4);
        u16x4 o;
        o[0] = f2b(v[0]); o[1] = f2b(v[1]); o[2] = f2b(v[2]); o[3] = f2b(v[3]);
        *reinterpret_cast<u16x4*>(dst + g * 4) = o;
    }
}

// ---------------------------------------------------------------------------
// 2) QKV GEMM  qkv[2048 x 6144] = x * [wq|wk|wv]^T.  (r12 version, reverted:
//    r13's 12-wave variant was neutral at identical MfmaUtil)
//    BM=256, BN=192, BK=64 -> grid (32,8) = 256 blocks. 8 waves 4M x 2N.
// ---------------------------------------------------------------------------
__global__ __launch_bounds__(512) void gemm_qkv(
    const unsigned short* __restrict__ A,    // xb  [2048 x 4096]
    const unsigned short* __restrict__ B0,   // wq  [4096 x 4096]
    const unsigned short* __restrict__ B1,   // wk  [1024 x 4096]
    const unsigned short* __restrict__ B2,   // wv  [1024 x 4096]
    unsigned short* __restrict__ C)          // qkv [2048 x 6144]
{
    constexpr int K = 4096, BK = 64, NT = K / BK;
    __shared__ unsigned short As[2][256 * 64];   // 64 KB
    __shared__ unsigned short Bs[2][192 * 64];   // 48 KB

    const int bm = blockIdx.y, bn = blockIdx.x;  // (32, 8): lin%8 == bn%8
    const int tid = threadIdx.x;
    const int w = tid >> 6, lane = tid & 63;
    const int wr = w >> 1, wc = w & 1;           // 4M x 2N
    const int r16 = lane & 15, g4 = lane >> 4;

    const int bn0 = bn * 192;
    const unsigned short* Ap = A + (size_t)bm * 256 * K;

    const int lrow = lane >> 3;   // 0..7 (row within 8-row unit)
    const int lchk = lane & 7;    // 0..7 (16B chunk within 128B row)

    f32x4 acc[4][6] = {};
    bf16x8 af[2][2], b0[3][2], b1[3][2];

    auto browbase = [&](int rowg) -> const unsigned short* {
        if (rowg < 4096) return B0 + (size_t)rowg * K;
        if (rowg < 5120) return B1 + (size_t)(rowg - 4096) * K;
        return B2 + (size_t)(rowg - 5120) * K;
    };

    auto stageA = [&](int buf, int tt, int half) {
        #pragma unroll
        for (int i = 0; i < 2; ++i) {
            const int j = i * 8 + w;                               // unit 0..15
            const int row0 = (j >> 2) * 64 + half * 32 + (j & 3) * 8;
            const int row = row0 + lrow;
            gload_lds16(Ap + (size_t)row * K + tt * BK + ((lchk ^ (row & 7)) * 8),
                        &As[buf][row0 * 64]);
        }
    };
    auto stageB = [&](int buf, int tt, int half) {
        #pragma unroll
        for (int i = 0; i < 2; ++i) {
            const int j = (i == 0) ? w : (8 + (w & 3));            // unit 0..11
            const int row0 = (j < 6) ? (half * 48 + j * 8)
                                     : (96 + half * 48 + (j - 6) * 8);
            const int row = row0 + lrow;
            const unsigned short* src = browbase(bn0 + row0) + (size_t)lrow * K;
            gload_lds16(src + tt * BK + ((lchk ^ (row & 7)) * 8),
                        &Bs[buf][row0 * 64]);
        }
    };
    auto readA = [&](int buf, int mh) {
        #pragma unroll
        for (int m = 0; m < 2; ++m)
            #pragma unroll
            for (int kk = 0; kk < 2; ++kk) {
                const int row = wr * 64 + mh * 32 + m * 16 + r16;
                af[m][kk] = *reinterpret_cast<const bf16x8*>(
                    &As[buf][row * 64 + (((kk * 4 + g4) ^ (row & 7)) * 8)]);
            }
    };
    auto readB = [&](int buf, int nh, bf16x8 (&br)[3][2]) {
        #pragma unroll
        for (int n = 0; n < 3; ++n)
            #pragma unroll
            for (int kk = 0; kk < 2; ++kk) {
                const int row = wc * 96 + nh * 48 + n * 16 + r16;
                br[n][kk] = *reinterpret_cast<const bf16x8*>(
                    &Bs[buf][row * 64 + (((kk * 4 + g4) ^ (row & 7)) * 8)]);
            }
    };
    auto mma = [&](bf16x8 (&br)[3][2], int mh, int nh) {
        __builtin_amdgcn_s_setprio(1);
        #pragma unroll
        for (int m = 0; m < 2; ++m)
            #pragma unroll
            for (int n = 0; n < 3; ++n)
                #pragma unroll
                for (int kk = 0; kk < 2; ++kk)
                    acc[mh * 2 + m][nh * 3 + n] = __builtin_amdgcn_mfma_f32_16x16x32_bf16(
                        af[m][kk], br[n][kk], acc[mh * 2 + m][nh * 3 + n], 0, 0, 0);
        __builtin_amdgcn_s_setprio(0);
    };

    // prologue (consumption order); leaves B-h1, A-h1 in flight = 4
    stageA(0, 0, 0); stageB(0, 0, 0); stageB(0, 0, 1); stageA(0, 0, 1);
    waitv<4>();
    BAR();

    for (int t = 0; t < NT - 1; ++t) {
        const int buf = t & 1;
        // ---- phase 0: Q(0,0) ----
        readA(buf, 0); readB(buf, 0, b0);
        stageA(buf ^ 1, t + 1, 0); stageB(buf ^ 1, t + 1, 0);
        BAR();
        mma(b0, 0, 0);
        waitv<6>();                 // 2LA+LB: B-h1(t) landed
        BAR();
        // ---- phase 1: Q(0,1) ----
        readB(buf, 1, b1);
        stageB(buf ^ 1, t + 1, 1);
        BAR();
        mma(b1, 0, 1);
        waitv<6>();                 // LA+2LB: A-h1(t) landed
        BAR();
        // ---- phase 2: Q(1,1) ----
        readA(buf, 1);
        stageA(buf ^ 1, t + 1, 1);
        BAR();
        mma(b1, 1, 1);
        BAR();
        // ---- phase 3: Q(1,0) ----
        mma(b0, 1, 0);
        waitv<4>();                 // LA+LB: A-h0(t+1), B-h0(t+1) landed
        BAR();
    }
    // ---- last tile (no staging; peeled vmcnt) ----
    {
        const int buf = (NT - 1) & 1;
        readA(buf, 0); readB(buf, 0, b0);
        BAR();
        mma(b0, 0, 0);
        waitv<2>();
        BAR();
        readB(buf, 1, b1);
        mma(b1, 0, 1);
        waitv<0>();
        readA(buf, 1);
        mma(b1, 1, 1);
        mma(b0, 1, 0);
    }

    // ---- epilogue ----
    const size_t crow0 = (size_t)bm * 256 + wr * 64;
    const size_t ccol0 = (size_t)bn0 + wc * 96;
    #pragma unroll
    for (int m = 0; m < 4; ++m)
        #pragma unroll
        for (int n = 0; n < 6; ++n)
            #pragma unroll
            for (int r = 0; r < 4; ++r)
                C[(crow0 + m * 16 + g4 * 4 + r) * QKVW + ccol0 + n * 16 + r16] =
                    f2b(acc[m][n][r]);
}

// ---------------------------------------------------------------------------
// 2b) O-proj GEMM  out[2048 x 4096] = ob * wo^T.  (unchanged from r9)
//     BM=128, BN=256, BK=64 -> grid (16,16) = 256 blocks. 8 waves 2M x 4N.
// ---------------------------------------------------------------------------
__global__ __launch_bounds__(512) void gemm_out(
    const unsigned short* __restrict__ A,   // ob  [2048 x 4096] bf16
    const unsigned short* __restrict__ B,   // wob [4096 x 4096] bf16
    float* __restrict__ C)                  // out [2048 x 4096] f32
{
    constexpr int K = 4096, BK = 64, NT = K / BK;
    __shared__ unsigned short As[2][128 * 64];   // 32 KB
    __shared__ unsigned short Bs[2][256 * 64];   // 64 KB

    const int bm = blockIdx.y, bn = blockIdx.x;  // (16, 16): lin%8 == bn%8
    const int tid = threadIdx.x;
    const int w = tid >> 6, lane = tid & 63;
    const int wr = w >> 2, wc = w & 3;           // 2M x 4N
    const int r16 = lane & 15, g4 = lane >> 4;

    const unsigned short* Ap = A + (size_t)bm * 128 * K;
    const unsigned short* Bp = B + (size_t)bn * 256 * K;

    const int lrow = lane >> 3;
    const int lchk = lane & 7;

    f32x4 acc[4][4] = {};
    bf16x8 af[2][2], b0[2][2], b1[2][2];

    auto stageA = [&](int buf, int tt, int half) {
        const int j = w;                                           // unit 0..7
        const int row0 = (j >> 2) * 64 + half * 32 + (j & 3) * 8;
        const int row = row0 + lrow;
        gload_lds16(Ap + (size_t)row * K + tt * BK + ((lchk ^ (row & 7)) * 8),
                    &As[buf][row0 * 64]);
    };
    auto stageB = [&](int buf, int tt, int half) {
        #pragma unroll
        for (int i = 0; i < 2; ++i) {
            const int j = i * 8 + w;                               // unit 0..15
            const int row0 = (j >> 2) * 64 + half * 32 + (j & 3) * 8;
            const int row = row0 + lrow;
            gload_lds16(Bp + (size_t)row * K + tt * BK + ((lchk ^ (row & 7)) * 8),
                        &Bs[buf][row0 * 64]);
        }
    };
    auto readA = [&](int buf, int mh) {
        #pragma unroll
        for (int m = 0; m < 2; ++m)
            #pragma unroll
            for (int kk = 0; kk < 2; ++kk) {
                const int row = wr * 64 + mh * 32 + m * 16 + r16;
                af[m][kk] = *reinterpret_cast<const bf16x8*>(
                    &As[buf][row * 64 + (((kk * 4 + g4) ^ (row & 7)) * 8)]);
            }
    };
    auto readB = [&](int buf, int nh, bf16x8 (&br)[2][2]) {
        #pragma unroll
        for (int n = 0; n < 2; ++n)
            #pragma unroll
            for (int kk = 0; kk < 2; ++kk) {
                const int row = wc * 64 + nh * 32 + n * 16 + r16;
                br[n][kk] = *reinterpret_cast<const bf16x8*>(
                    &Bs[buf][row * 64 + (((kk * 4 + g4) ^ (row & 7)) * 8)]);
            }
    };
    auto mma = [&](bf16x8 (&br)[2][2], int mh, int nh) {
        __builtin_amdgcn_s_setprio(1);
        #pragma unroll
        for (int m = 0; m < 2; ++m)
            #pragma unroll
            for (int n = 0; n < 2; ++n)
                #pragma unroll
                for (int kk = 0; kk < 2; ++kk)
                    acc[mh * 2 + m][nh * 2 + n] = __builtin_amdgcn_mfma_f32_16x16x32_bf16(
                        af[m][kk], br[n][kk], acc[mh * 2 + m][nh * 2 + n], 0, 0, 0);
        __builtin_amdgcn_s_setprio(0);
    };

    stageA(0, 0, 0); stageB(0, 0, 0); stageB(0, 0, 1); stageA(0, 0, 1);
    waitv<3>();                     // LA+LB
    BAR();

    for (int t = 0; t < NT - 1; ++t) {
        const int buf = t & 1;
        readA(buf, 0); readB(buf, 0, b0);
        stageA(buf ^ 1, t + 1, 0); stageB(buf ^ 1, t + 1, 0);
        BAR();
        mma(b0, 0, 0);
        waitv<4>();                 // 2LA+LB
        BAR();
        readB(buf, 1, b1);
        stageB(buf ^ 1, t + 1, 1);
        BAR();
        mma(b1, 0, 1);
        waitv<5>();                 // LA+2LB
        BAR();
        readA(buf, 1);
        stageA(buf ^ 1, t + 1, 1);
        BAR();
        mma(b1, 1, 1);
        BAR();
        mma(b0, 1, 0);
        waitv<3>();                 // LA+LB
        BAR();
    }
    {
        const int buf = (NT - 1) & 1;
        readA(buf, 0); readB(buf, 0, b0);
        BAR();
        mma(b0, 0, 0);
        waitv<1>();
        BAR();
        readB(buf, 1, b1);
        mma(b1, 0, 1);
        waitv<0>();
        readA(buf, 1);
        mma(b1, 1, 1);
        mma(b0, 1, 0);
    }

    const size_t crow0 = (size_t)bm * 128 + wr * 64;
    const size_t ccol0 = (size_t)bn * 256 + wc * 64;
    #pragma unroll
    for (int m = 0; m < 4; ++m)
        #pragma unroll
        for (int n = 0; n < 4; ++n)
            #pragma unroll
            for (int r = 0; r < 4; ++r)
                C[(crow0 + m * 16 + g4 * 4 + r) * DD + ccol0 + n * 16 + r16] = acc[m][n][r];
}

// ---------------------------------------------------------------------------
// 3) RoPE in-place on q/k cols of qkv. Q part scaled by log2(e)/sqrt(HD).
// ---------------------------------------------------------------------------
__global__ __launch_bounds__(256) void rope_kernel(unsigned short* __restrict__ qkv,
                                                   const float* __restrict__ fc,
                                                   const float* __restrict__ fs) {
    constexpr float QSCALE = 0.08838834764831845f * 1.4426950408889634f; // 1/sqrt(128)*log2(e)
    const int g = blockIdx.x * 256 + threadIdx.x;     // 0..767, groups of 8 cols
    if (g >= 640) return;
    const int s = blockIdx.y;
    const int col = g * 8;                            // within first 5120 cols
    unsigned short* p = qkv + (size_t)s * QKVW + col;
    u16x8 v = *reinterpret_cast<const u16x8*>(p);
    const int i0 = (col & 127) >> 1;
    f32x4 c  = *reinterpret_cast<const f32x4*>(fc + s * 64 + i0);
    f32x4 sn = *reinterpret_cast<const f32x4*>(fs + s * 64 + i0);
    const float post = (col < DD) ? QSCALE : 1.0f;
    u16x8 o;
    #pragma unroll
    for (int j = 0; j < 4; ++j) {
        float e  = b2f(v[2*j]);
        float od = b2f(v[2*j+1]);
        o[2*j]   = f2b((e * c[j] - od * sn[j]) * post);
        o[2*j+1] = f2b((e * sn[j] + od * c[j]) * post);
    }
    *reinterpret_cast<u16x8*>(p) = o;
}

// ---------------------------------------------------------------------------
// 4) Transpose V part of qkv (cols 5120..6144) into Vt[kvh][128][S2]
// ---------------------------------------------------------------------------
__global__ __launch_bounds__(256) void transpose_v(const unsigned short* __restrict__ qkv,
                                                   unsigned short* __restrict__ Vt) {
    __shared__ unsigned short tile[64][72];
    const int d0g = blockIdx.x * 64;
    const int s0  = blockIdx.y * 64;
    const int kvh = d0g >> 7, dl0 = d0g & 127;
    const int tid = threadIdx.x;
    #pragma unroll
    for (int p = 0; p < 2; ++p) {
        const int sgi = p * 256 + tid;
        const int srow = sgi >> 3, dseg = sgi & 7;
        u16x8 v = *reinterpret_cast<const u16x8*>(
            qkv + (size_t)(s0 + srow) * QKVW + 5120 + d0g + dseg * 8);
        #pragma unroll
        for (int j = 0; j < 8; ++j) tile[srow][dseg * 8 + j] = v[j];
    }
    __syncthreads();
    #pragma unroll
    for (int p = 0; p < 2; ++p) {
        const int sgi = p * 256 + tid;
        const int drow = sgi >> 3, sseg = sgi & 7;
        u16x8 v;
        #pragma unroll
        for (int j = 0; j < 8; ++j) v[j] = tile[sseg * 8 + j][drow];
        *reinterpret_cast<u16x8*>(
            Vt + (size_t)kvh * HD2 * S2 + (size_t)(dl0 + drow) * S2 + s0 + sseg * 8) = v;
    }
}

// ---------------------------------------------------------------------------
// 5) Flash attention v9: r12 complement-pair blocks + PAIRED-KV processing.
//    One softmax pass + one barrier/drain per 128 kv (two 64-kv tiles),
//    halving the per-kv softmax and sync overhead vs r12. Memory plan is
//    r12-style double buffering at PAIR granularity: 4 K-slots + 4 V-slots;
//    pair j reads slots {2j&3,(2j+1)&3}, stages pair j+1 into the other two,
//    one WAITV(0)+syncthreads per pair. P buffer (4KB/wave) reused serially
//    per 64-half (same-wave in-order LDS). have1=false path is arithmetic-
//    identical to r12's single-tile path. LDS = 64K + 64V + 32P = 160 KB.
// ---------------------------------------------------------------------------
__global__ __launch_bounds__(512) void attn_kernel(const unsigned short* __restrict__ Qkv,
                                                   const unsigned short* __restrict__ Vt,
                                                   unsigned short* __restrict__ O) {
    __shared__ unsigned short Klds[4][64 * 128];   // 64 KB
    __shared__ unsigned short Vlds[4][128 * 64];   // 64 KB
    __shared__ unsigned short Plds[8][2048];       // 32 KB (4 KB/wave)

    const int kvh = blockIdx.x;                  // 0..7
    const int h   = kvh * 4 + (blockIdx.y & 3);
    const int p   = blockIdx.y >> 2;             // pair id 0..7
    const int cB  = 8 + p, cS = 7 - p;           // complement chunks
    const int w = threadIdx.x >> 6, lane = threadIdx.x & 63;
    const int r16 = lane & 15, g4 = lane >> 4;

    const int myc = (w < 4) ? cB : cS;
    const int qw  = myc * 128 + (w & 3) * 32;    // wave's first q row
    const int np  = cB + 1;                      // 128-kv pairs staged (ntB = 2cB+2)

    const unsigned short* Kbase = Qkv + DD + kvh * HD2;      // + kv*QKVW + d
    const unsigned short* Vtb   = Vt + (size_t)kvh * HD2 * S2;
    char* pw = (char*)(&Plds[w][0]);             // wave's 4KB P region

    // staging lane constants
    const int krow_l = lane >> 4;      // row within 4-row segment
    const int kchunk = lane & 15;      // 16B chunk within 256B K row
    const int vd_l   = lane >> 3;      // d within 8-row segment
    const int vchunk = lane & 7;       // 16B chunk within 128B V row

    // Q fragments (B-frag of swapped QK^T): rows qw+m*16+r16, d-slices f*32+g4*8
    bf16x8 qf[2][4];
    #pragma unroll
    for (int m = 0; m < 2; ++m)
        #pragma unroll
        for (int f = 0; f < 4; ++f)
            qf[m][f] = *reinterpret_cast<const bf16x8*>(
                Qkv + (size_t)(qw + m * 16 + r16) * QKVW + h * HD2 + f * 32 + g4 * 8);

    f32x4 o[2][8] = {};
    float mr[2] = {-3e38f, -3e38f};   // running max (log2 units) for q = m*16+r16
    float lr[2] = {0.f, 0.f};

    auto stagePair = [&](int slot0, int kv0) {   // 8 loads/wave (2 tiles x (2K+2V))
        #pragma unroll
        for (int tt = 0; tt < 2; ++tt) {
            const int slot = slot0 + tt;
            const int kvb = kv0 + tt * 64;
            #pragma unroll
            for (int i = 0; i < 2; ++i) {
                const int seg = i * 8 + w;                 // 0..15
                const int row = seg * 4 + krow_l;          // kv row 0..63
                gload_lds16(Kbase + (size_t)(kvb + row) * QKVW + ((kchunk ^ (row & 7)) * 8),
                            &Klds[slot][seg * 512]);
            }
            #pragma unroll
            for (int i = 0; i < 2; ++i) {
                const int seg = i * 8 + w;
                const int d = seg * 8 + vd_l;              // d row 0..127
                gload_lds16(Vtb + (size_t)d * S2 + kvb + ((vchunk ^ (d & 7)) * 8),
                            &Vlds[slot][seg * 512]);
            }
        }
    };

    auto qkt = [&](int slot, int kvb, float (&svt)[2][4][4]) {
        f32x4 sa[2][4] = {};
        #pragma unroll
        for (int kb = 0; kb < 4; ++kb) {
            bf16x8 kf[4];
            #pragma unroll
            for (int f = 0; f < 4; ++f)
                kf[f] = *reinterpret_cast<const bf16x8*>(
                    &Klds[slot][(kb * 16 + r16) * 128 + (((f * 4 + g4) ^ (r16 & 7)) * 8)]);
            __builtin_amdgcn_s_setprio(1);
            #pragma unroll
            for (int m = 0; m < 2; ++m)
                #pragma unroll
                for (int f = 0; f < 4; ++f)
                    sa[m][kb] = __builtin_amdgcn_mfma_f32_16x16x32_bf16(
                        kf[f], qf[m][f], sa[m][kb], 0, 0, 0);
            __builtin_amdgcn_s_setprio(0);
        }
        const bool needmask = (kvb + 63 > qw);
        #pragma unroll
        for (int m = 0; m < 2; ++m)
            #pragma unroll
            for (int kb = 0; kb < 4; ++kb)
                #pragma unroll
                for (int r = 0; r < 4; ++r) {
                    float xx = sa[m][kb][r];
                    if (needmask) {
                        const int kvg = kvb + kb * 16 + g4 * 4 + r;
                        const int qg  = qw + m * 16 + r16;
                        xx = (kvg > qg) ? -3e38f : xx;
                    }
                    svt[m][kb][r] = xx;
                }
    };

    auto pv = [&](int slot, float (&svt)[2][4][4]) {
        #pragma unroll
        for (int m = 0; m < 2; ++m)
            #pragma unroll
            for (int kb = 0; kb < 4; ++kb) {
                const unsigned w0 = cvt_pk_bf16(svt[m][kb][0], svt[m][kb][1]);
                const unsigned w1 = cvt_pk_bf16(svt[m][kb][2], svt[m][kb][3]);
                int wa = m * 2048 + ((kb * 2) + (g4 >> 1)) * 256 + r16 * 16 + (g4 & 1) * 8;
                wa ^= (r16 >> 3) << 4;
                *reinterpret_cast<unsigned long long*>(pw + wa) =
                    (unsigned long long)w0 | ((unsigned long long)w1 << 32);
            }
        asm volatile("s_waitcnt lgkmcnt(0)" ::: "memory");
        bf16x8 pa[2][2];
        #pragma unroll
        for (int m = 0; m < 2; ++m)
            #pragma unroll
            for (int kvs = 0; kvs < 2; ++kvs) {
                int ra = m * 2048 + kvs * 1024 + lane * 16;
                ra ^= (r16 >> 3) << 4;
                pa[m][kvs] = *reinterpret_cast<const bf16x8*>(pw + ra);
            }
        #pragma unroll
        for (int kvs = 0; kvs < 2; ++kvs)
            #pragma unroll
            for (int n = 0; n < 8; ++n) {
                const bf16x8 vb = *reinterpret_cast<const bf16x8*>(
                    &Vlds[slot][(n * 16 + r16) * 64 + (((kvs * 4 + g4) ^ (r16 & 7)) * 8)]);
                __builtin_amdgcn_s_setprio(1);
                #pragma unroll
                for (int m = 0; m < 2; ++m)
                    o[m][n] = __builtin_amdgcn_mfma_f32_16x16x32_bf16(
                        pa[m][kvs], vb, o[m][n], 0, 0, 0);
                __builtin_amdgcn_s_setprio(0);
            }
    };

    // prologue: stage pair 0 (tiles 0,1 -> slots 0,1)
    stagePair(0, 0);
    WAITV(0);
    __syncthreads();

    for (int j = 0; j < np; ++j) {
        const int s0 = (j & 1) * 2;              // this pair's slots {s0, s0+1}
        const int kv0 = j * 128;
        if (j + 1 < np) stagePair(s0 ^ 2, kv0 + 128);

        if (kv0 <= qw + 31) {                    // wave needs tile 2j
            const bool have1 = (kv0 + 64 <= qw + 31);   // wave needs tile 2j+1
            float sv0[2][4][4], sv1[2][4][4];
            qkt(s0, kv0, sv0);
            if (have1) qkt(s0 + 1, kv0 + 64, sv1);

            // ---- combined row max over the pair ----
            float rowm[2];
            #pragma unroll
            for (int m = 0; m < 2; ++m) {
                float a0 = fmaxf(fmaxf(sv0[m][0][0], sv0[m][0][1]), fmaxf(sv0[m][0][2], sv0[m][0][3]));
                float a1 = fmaxf(fmaxf(sv0[m][1][0], sv0[m][1][1]), fmaxf(sv0[m][1][2], sv0[m][1][3]));
                float a2 = fmaxf(fmaxf(sv0[m][2][0], sv0[m][2][1]), fmaxf(sv0[m][2][2], sv0[m][2][3]));
                float a3 = fmaxf(fmaxf(sv0[m][3][0], sv0[m][3][1]), fmaxf(sv0[m][3][2], sv0[m][3][3]));
                rowm[m] = fmaxf(fmaxf(a0, a1), fmaxf(a2, a3));
            }
            if (have1) {
                #pragma unroll
                for (int m = 0; m < 2; ++m) {
                    float a0 = fmaxf(fmaxf(sv1[m][0][0], sv1[m][0][1]), fmaxf(sv1[m][0][2], sv1[m][0][3]));
                    float a1 = fmaxf(fmaxf(sv1[m][1][0], sv1[m][1][1]), fmaxf(sv1[m][1][2], sv1[m][1][3]));
                    float a2 = fmaxf(fmaxf(sv1[m][2][0], sv1[m][2][1]), fmaxf(sv1[m][2][2], sv1[m][2][3]));
                    float a3 = fmaxf(fmaxf(sv1[m][3][0], sv1[m][3][1]), fmaxf(sv1[m][3][2], sv1[m][3][3]));
                    rowm[m] = fmaxf(rowm[m], fmaxf(fmaxf(a0, a1), fmaxf(a2, a3)));
                }
            }
            #pragma unroll
            for (int m = 0; m < 2; ++m) {
                rowm[m] = fmaxf(rowm[m], __shfl_xor(rowm[m], 16));
                rowm[m] = fmaxf(rowm[m], __shfl_xor(rowm[m], 32));
            }
            // ---- defer-max (T13, base-2 THR = 11.5 ~ e^8) ----
            const float gmax = fmaxf(rowm[0] - mr[0], rowm[1] - mr[1]);
            if (!__all(gmax <= 11.5f)) {
                float corr[2];
                #pragma unroll
                for (int m = 0; m < 2; ++m) {
                    const float mn = fmaxf(mr[m], rowm[m]);
                    corr[m] = exp2f(mr[m] - mn);
                    mr[m] = mn;
                    lr[m] *= corr[m];
                }
                #pragma unroll
                for (int m = 0; m < 2; ++m)
                    #pragma unroll
                    for (int r = 0; r < 4; ++r) {
                        const float co = __shfl(corr[m], (lane & 48) | (g4 * 4 + r));
                        #pragma unroll
                        for (int n = 0; n < 8; ++n) o[m][n][r] *= co;
                    }
            }
            // ---- P = exp2(S - m), row sums over the pair ----
            float rsum[2] = {0.f, 0.f};
            #pragma unroll
            for (int m = 0; m < 2; ++m)
                #pragma unroll
                for (int kb = 0; kb < 4; ++kb)
                    #pragma unroll
                    for (int r = 0; r < 4; ++r) {
                        const float pp = exp2f(sv0[m][kb][r] - mr[m]);
                        sv0[m][kb][r] = pp;
                        rsum[m] += pp;
                    }
            if (have1) {
                #pragma unroll
                for (int m = 0; m < 2; ++m)
                    #pragma unroll
                    for (int kb = 0; kb < 4; ++kb)
                        #pragma unroll
                        for (int r = 0; r < 4; ++r) {
                            const float pp = exp2f(sv1[m][kb][r] - mr[m]);
                            sv1[m][kb][r] = pp;
                            rsum[m] += pp;
                        }
            }
            #pragma unroll
            for (int m = 0; m < 2; ++m) {
                rsum[m] += __shfl_xor(rsum[m], 16);
                rsum[m] += __shfl_xor(rsum[m], 32);
                lr[m] += rsum[m];
            }
            // ---- PV per half (P buffer reused serially) ----
            pv(s0, sv0);
            if (have1) pv(s0 + 1, sv1);
        }

        WAITV(0);
        __syncthreads();
    }

    // ---- normalize (broadcast 1/lr to o-layout lanes) + write ----
    float inv[2];
    #pragma unroll
    for (int m = 0; m < 2; ++m) inv[m] = 1.0f / lr[m];
    #pragma unroll
    for (int m = 0; m < 2; ++m)
        #pragma unroll
        for (int r = 0; r < 4; ++r) {
            const float iv = __shfl(inv[m], (lane & 48) | (g4 * 4 + r));
            #pragma unroll
            for (int n = 0; n < 8; ++n)
                O[(size_t)(qw + m * 16 + g4 * 4 + r) * DD + h * HD2 + n * 16 + r16] =
                    f2b(o[m][n][r] * iv);
        }
}

// ---------------------------------------------------------------------------
extern "C" void kernel_launch(void* const* d_in, const int* in_sizes, int n_in,
                              void* d_out, int out_size, void* d_ws, size_t ws_size,
                              hipStream_t stream) {
    (void)in_sizes; (void)n_in; (void)out_size; (void)ws_size;
    const float* x  = (const float*)d_in[0];
    const float* wq = (const float*)d_in[1];
    const float* wk = (const float*)d_in[2];
    const float* wv = (const float*)d_in[3];
    const float* wo = (const float*)d_in[4];
    // d_in[5] = mask (causal tril; computed analytically in-kernel)
    const float* fc = (const float*)d_in[6];
    const float* fs = (const float*)d_in[7];
    float* out = (float*)d_out;

    unsigned short* ws = (unsigned short*)d_ws;
    const size_t M1 = 1024 * 1024;
    unsigned short* xb  = ws;              // 8M  (x bf16)
    unsigned short* wqb = ws + 8  * M1;    // 16M
    unsigned short* wkb = ws + 24 * M1;    // 4M
    unsigned short* wvb = ws + 28 * M1;    // 4M
    unsigned short* wob = ws + 32 * M1;    // 16M
    unsigned short* qkv = ws + 48 * M1;    // 12M (S x 6144)
    unsigned short* vt  = ws + 60 * M1;    // 2M  (KVH x 128 x S)
    unsigned short* ob  = ws + 62 * M1;    // 8M  (S x 4096)

    cvt_all<<<2048, 256, 0, stream>>>(x, wq, wk, wv, wo, ws);
    gemm_qkv<<<dim3(32, 8), 512, 0, stream>>>(xb, wqb, wkb, wvb, qkv);
    rope_kernel<<<dim3(3, 2048), 256, 0, stream>>>(qkv, fc, fs);
    transpose_v<<<dim3(16, 32), 256, 0, stream>>>(qkv, vt);
    attn_kernel<<<dim3(8, 32), 512, 0, stream>>>(qkv, vt, ob);
    gemm_out<<<dim3(16, 16), 512, 0, stream>>>(ob, wob, out);
}

// Round 15
// 293.994 us; speedup vs baseline: 1.0267x; 1.0223x over previous
//
#include <hip/hip_runtime.h>
#include <hip/hip_bf16.h>
#include <stdint.h>

// Problem constants
#define S2   2048
#define DD   4096
#define NH   32
#define NKVH 8
#define HD2  128
// qkv buffer row width: 4096 (q) + 1024 (k) + 1024 (v)
#define QKVW 6144

typedef __bf16 bf16x8 __attribute__((ext_vector_type(8)));
typedef float  f32x4  __attribute__((ext_vector_type(4)));
typedef unsigned short u16x8 __attribute__((ext_vector_type(8)));
typedef unsigned short u16x4 __attribute__((ext_vector_type(4)));

__device__ __forceinline__ unsigned short f2b(float f) {
    unsigned int u = __builtin_bit_cast(unsigned int, f);
    unsigned int r = (u + 0x7FFFu + ((u >> 16) & 1u)) >> 16;   // RNE
    return (unsigned short)r;
}
__device__ __forceinline__ float b2f(unsigned short h) {
    unsigned int u = ((unsigned int)h) << 16;
    return __builtin_bit_cast(float, u);
}
__device__ __forceinline__ unsigned cvt_pk_bf16(float a, float b) {
    unsigned r;
    asm("v_cvt_pk_bf16_f32 %0, %1, %2" : "=v"(r) : "v"(a), "v"(b));
    return r;   // lo16 = bf16(a), hi16 = bf16(b)
}

// global -> LDS direct copy, 16B per lane. LDS dest is wave-uniform base + lane*16.
__device__ __forceinline__ void gload_lds16(const void* g, void* lds) {
    __builtin_amdgcn_global_load_lds(
        (const __attribute__((address_space(1))) void*)(uintptr_t)g,
        (__attribute__((address_space(3))) void*)(uint32_t)(uintptr_t)lds,
        16, 0, 0);
}

// raw barrier (no vmcnt drain) + compiler memory fences so LDS ops don't cross
#define BAR() do { asm volatile("" ::: "memory"); \
                   __builtin_amdgcn_s_barrier();  \
                   asm volatile("" ::: "memory"); } while (0)
#define WAITV(n) asm volatile("s_waitcnt vmcnt(" #n ")" ::: "memory")

template<int N> __device__ __forceinline__ void waitv() {
    if      constexpr (N == 0)  WAITV(0);
    else if constexpr (N == 1)  WAITV(1);
    else if constexpr (N == 2)  WAITV(2);
    else if constexpr (N == 3)  WAITV(3);
    else if constexpr (N == 4)  WAITV(4);
    else if constexpr (N == 5)  WAITV(5);
    else if constexpr (N == 6)  WAITV(6);
    else if constexpr (N == 8)  WAITV(8);
}

// ---------------------------------------------------------------------------
// 1) fp32 -> bf16 conversion for x, wq, wk, wv (wo is converted inside attn)
// ---------------------------------------------------------------------------
__global__ void cvt_all(const float* __restrict__ x,  const float* __restrict__ wq,
                        const float* __restrict__ wk, const float* __restrict__ wv,
                        unsigned short* __restrict__ dst) {
    const long long NG = 8LL * 1024 * 1024;   // float4 groups (x 2M | wq 4M | wk 1M | wv 1M)
    const long long stride = (long long)gridDim.x * blockDim.x;
    for (long long g = (long long)blockIdx.x * blockDim.x + threadIdx.x; g < NG; g += stride) {
        const float* src; long long off;
        if      (g < 2LL*1024*1024) { src = x;  off = g; }
        else if (g < 6LL*1024*1024) { src = wq; off = g - 2LL*1024*1024; }
        else if (g < 7LL*1024*1024) { src = wk; off = g - 6LL*1024*1024; }
        else                        { src = wv; off = g - 7LL*1024*1024; }
        f32x4 v = *reinterpret_cast<const f32x4*>(src + off * 4);
        u16x4 o;
        o[0] = f2b(v[0]); o[1] = f2b(v[1]); o[2] = f2b(v[2]); o[3] = f2b(v[3]);
        *reinterpret_cast<u16x4*>(dst + g * 4) = o;
    }
}

// ---------------------------------------------------------------------------
// 2) QKV GEMM  qkv[2048 x 6144] = x * [wq|wk|wv]^T.  (r12, unchanged)
//    BM=256, BN=192, BK=64 -> grid (32,8) = 256 blocks. 8 waves 4M x 2N.
// ---------------------------------------------------------------------------
__global__ __launch_bounds__(512) void gemm_qkv(
    const unsigned short* __restrict__ A,    // xb  [2048 x 4096]
    const unsigned short* __restrict__ B0,   // wq  [4096 x 4096]
    const unsigned short* __restrict__ B1,   // wk  [1024 x 4096]
    const unsigned short* __restrict__ B2,   // wv  [1024 x 4096]
    unsigned short* __restrict__ C)          // qkv [2048 x 6144]
{
    constexpr int K = 4096, BK = 64, NT = K / BK;
    __shared__ unsigned short As[2][256 * 64];   // 64 KB
    __shared__ unsigned short Bs[2][192 * 64];   // 48 KB

    const int bm = blockIdx.y, bn = blockIdx.x;  // (32, 8): lin%8 == bn%8
    const int tid = threadIdx.x;
    const int w = tid >> 6, lane = tid & 63;
    const int wr = w >> 1, wc = w & 1;           // 4M x 2N
    const int r16 = lane & 15, g4 = lane >> 4;

    const int bn0 = bn * 192;
    const unsigned short* Ap = A + (size_t)bm * 256 * K;

    const int lrow = lane >> 3;   // 0..7 (row within 8-row unit)
    const int lchk = lane & 7;    // 0..7 (16B chunk within 128B row)

    f32x4 acc[4][6] = {};
    bf16x8 af[2][2], b0[3][2], b1[3][2];

    auto browbase = [&](int rowg) -> const unsigned short* {
        if (rowg < 4096) return B0 + (size_t)rowg * K;
        if (rowg < 5120) return B1 + (size_t)(rowg - 4096) * K;
        return B2 + (size_t)(rowg - 5120) * K;
    };

    auto stageA = [&](int buf, int tt, int half) {
        #pragma unroll
        for (int i = 0; i < 2; ++i) {
            const int j = i * 8 + w;                               // unit 0..15
            const int row0 = (j >> 2) * 64 + half * 32 + (j & 3) * 8;
            const int row = row0 + lrow;
            gload_lds16(Ap + (size_t)row * K + tt * BK + ((lchk ^ (row & 7)) * 8),
                        &As[buf][row0 * 64]);
        }
    };
    auto stageB = [&](int buf, int tt, int half) {
        #pragma unroll
        for (int i = 0; i < 2; ++i) {
            const int j = (i == 0) ? w : (8 + (w & 3));            // unit 0..11
            const int row0 = (j < 6) ? (half * 48 + j * 8)
                                     : (96 + half * 48 + (j - 6) * 8);
            const int row = row0 + lrow;
            const unsigned short* src = browbase(bn0 + row0) + (size_t)lrow * K;
            gload_lds16(src + tt * BK + ((lchk ^ (row & 7)) * 8),
                        &Bs[buf][row0 * 64]);
        }
    };
    auto readA = [&](int buf, int mh) {
        #pragma unroll
        for (int m = 0; m < 2; ++m)
            #pragma unroll
            for (int kk = 0; kk < 2; ++kk) {
                const int row = wr * 64 + mh * 32 + m * 16 + r16;
                af[m][kk] = *reinterpret_cast<const bf16x8*>(
                    &As[buf][row * 64 + (((kk * 4 + g4) ^ (row & 7)) * 8)]);
            }
    };
    auto readB = [&](int buf, int nh, bf16x8 (&br)[3][2]) {
        #pragma unroll
        for (int n = 0; n < 3; ++n)
            #pragma unroll
            for (int kk = 0; kk < 2; ++kk) {
                const int row = wc * 96 + nh * 48 + n * 16 + r16;
                br[n][kk] = *reinterpret_cast<const bf16x8*>(
                    &Bs[buf][row * 64 + (((kk * 4 + g4) ^ (row & 7)) * 8)]);
            }
    };
    auto mma = [&](bf16x8 (&br)[3][2], int mh, int nh) {
        __builtin_amdgcn_s_setprio(1);
        #pragma unroll
        for (int m = 0; m < 2; ++m)
            #pragma unroll
            for (int n = 0; n < 3; ++n)
                #pragma unroll
                for (int kk = 0; kk < 2; ++kk)
                    acc[mh * 2 + m][nh * 3 + n] = __builtin_amdgcn_mfma_f32_16x16x32_bf16(
                        af[m][kk], br[n][kk], acc[mh * 2 + m][nh * 3 + n], 0, 0, 0);
        __builtin_amdgcn_s_setprio(0);
    };

    // prologue (consumption order); leaves B-h1, A-h1 in flight = 4
    stageA(0, 0, 0); stageB(0, 0, 0); stageB(0, 0, 1); stageA(0, 0, 1);
    waitv<4>();
    BAR();

    for (int t = 0; t < NT - 1; ++t) {
        const int buf = t & 1;
        // ---- phase 0: Q(0,0) ----
        readA(buf, 0); readB(buf, 0, b0);
        stageA(buf ^ 1, t + 1, 0); stageB(buf ^ 1, t + 1, 0);
        BAR();
        mma(b0, 0, 0);
        waitv<6>();                 // 2LA+LB: B-h1(t) landed
        BAR();
        // ---- phase 1: Q(0,1) ----
        readB(buf, 1, b1);
        stageB(buf ^ 1, t + 1, 1);
        BAR();
        mma(b1, 0, 1);
        waitv<6>();                 // LA+2LB: A-h1(t) landed
        BAR();
        // ---- phase 2: Q(1,1) ----
        readA(buf, 1);
        stageA(buf ^ 1, t + 1, 1);
        BAR();
        mma(b1, 1, 1);
        BAR();
        // ---- phase 3: Q(1,0) ----
        mma(b0, 1, 0);
        waitv<4>();                 // LA+LB: A-h0(t+1), B-h0(t+1) landed
        BAR();
    }
    // ---- last tile (no staging; peeled vmcnt) ----
    {
        const int buf = (NT - 1) & 1;
        readA(buf, 0); readB(buf, 0, b0);
        BAR();
        mma(b0, 0, 0);
        waitv<2>();
        BAR();
        readB(buf, 1, b1);
        mma(b1, 0, 1);
        waitv<0>();
        readA(buf, 1);
        mma(b1, 1, 1);
        mma(b0, 1, 0);
    }

    // ---- epilogue ----
    const size_t crow0 = (size_t)bm * 256 + wr * 64;
    const size_t ccol0 = (size_t)bn0 + wc * 96;
    #pragma unroll
    for (int m = 0; m < 4; ++m)
        #pragma unroll
        for (int n = 0; n < 6; ++n)
            #pragma unroll
            for (int r = 0; r < 4; ++r)
                C[(crow0 + m * 16 + g4 * 4 + r) * QKVW + ccol0 + n * 16 + r16] =
                    f2b(acc[m][n][r]);
}

// ---------------------------------------------------------------------------
// 2b) O-proj GEMM  out[2048 x 4096] = ob * wo^T.  (unchanged from r9)
//     BM=128, BN=256, BK=64 -> grid (16,16) = 256 blocks. 8 waves 2M x 4N.
// ---------------------------------------------------------------------------
__global__ __launch_bounds__(512) void gemm_out(
    const unsigned short* __restrict__ A,   // ob  [2048 x 4096] bf16
    const unsigned short* __restrict__ B,   // wob [4096 x 4096] bf16
    float* __restrict__ C)                  // out [2048 x 4096] f32
{
    constexpr int K = 4096, BK = 64, NT = K / BK;
    __shared__ unsigned short As[2][128 * 64];   // 32 KB
    __shared__ unsigned short Bs[2][256 * 64];   // 64 KB

    const int bm = blockIdx.y, bn = blockIdx.x;  // (16, 16): lin%8 == bn%8
    const int tid = threadIdx.x;
    const int w = tid >> 6, lane = tid & 63;
    const int wr = w >> 2, wc = w & 3;           // 2M x 4N
    const int r16 = lane & 15, g4 = lane >> 4;

    const unsigned short* Ap = A + (size_t)bm * 128 * K;
    const unsigned short* Bp = B + (size_t)bn * 256 * K;

    const int lrow = lane >> 3;
    const int lchk = lane & 7;

    f32x4 acc[4][4] = {};
    bf16x8 af[2][2], b0[2][2], b1[2][2];

    auto stageA = [&](int buf, int tt, int half) {
        const int j = w;                                           // unit 0..7
        const int row0 = (j >> 2) * 64 + half * 32 + (j & 3) * 8;
        const int row = row0 + lrow;
        gload_lds16(Ap + (size_t)row * K + tt * BK + ((lchk ^ (row & 7)) * 8),
                    &As[buf][row0 * 64]);
    };
    auto stageB = [&](int buf, int tt, int half) {
        #pragma unroll
        for (int i = 0; i < 2; ++i) {
            const int j = i * 8 + w;                               // unit 0..15
            const int row0 = (j >> 2) * 64 + half * 32 + (j & 3) * 8;
            const int row = row0 + lrow;
            gload_lds16(Bp + (size_t)row * K + tt * BK + ((lchk ^ (row & 7)) * 8),
                        &Bs[buf][row0 * 64]);
        }
    };
    auto readA = [&](int buf, int mh) {
        #pragma unroll
        for (int m = 0; m < 2; ++m)
            #pragma unroll
            for (int kk = 0; kk < 2; ++kk) {
                const int row = wr * 64 + mh * 32 + m * 16 + r16;
                af[m][kk] = *reinterpret_cast<const bf16x8*>(
                    &As[buf][row * 64 + (((kk * 4 + g4) ^ (row & 7)) * 8)]);
            }
    };
    auto readB = [&](int buf, int nh, bf16x8 (&br)[2][2]) {
        #pragma unroll
        for (int n = 0; n < 2; ++n)
            #pragma unroll
            for (int kk = 0; kk < 2; ++kk) {
                const int row = wc * 64 + nh * 32 + n * 16 + r16;
                br[n][kk] = *reinterpret_cast<const bf16x8*>(
                    &Bs[buf][row * 64 + (((kk * 4 + g4) ^ (row & 7)) * 8)]);
            }
    };
    auto mma = [&](bf16x8 (&br)[2][2], int mh, int nh) {
        __builtin_amdgcn_s_setprio(1);
        #pragma unroll
        for (int m = 0; m < 2; ++m)
            #pragma unroll
            for (int n = 0; n < 2; ++n)
                #pragma unroll
                for (int kk = 0; kk < 2; ++kk)
                    acc[mh * 2 + m][nh * 2 + n] = __builtin_amdgcn_mfma_f32_16x16x32_bf16(
                        af[m][kk], br[n][kk], acc[mh * 2 + m][nh * 2 + n], 0, 0, 0);
        __builtin_amdgcn_s_setprio(0);
    };

    stageA(0, 0, 0); stageB(0, 0, 0); stageB(0, 0, 1); stageA(0, 0, 1);
    waitv<3>();                     // LA+LB
    BAR();

    for (int t = 0; t < NT - 1; ++t) {
        const int buf = t & 1;
        readA(buf, 0); readB(buf, 0, b0);
        stageA(buf ^ 1, t + 1, 0); stageB(buf ^ 1, t + 1, 0);
        BAR();
        mma(b0, 0, 0);
        waitv<4>();                 // 2LA+LB
        BAR();
        readB(buf, 1, b1);
        stageB(buf ^ 1, t + 1, 1);
        BAR();
        mma(b1, 0, 1);
        waitv<5>();                 // LA+2LB
        BAR();
        readA(buf, 1);
        stageA(buf ^ 1, t + 1, 1);
        BAR();
        mma(b1, 1, 1);
        BAR();
        mma(b0, 1, 0);
        waitv<3>();                 // LA+LB
        BAR();
    }
    {
        const int buf = (NT - 1) & 1;
        readA(buf, 0); readB(buf, 0, b0);
        BAR();
        mma(b0, 0, 0);
        waitv<1>();
        BAR();
        readB(buf, 1, b1);
        mma(b1, 0, 1);
        waitv<0>();
        readA(buf, 1);
        mma(b1, 1, 1);
        mma(b0, 1, 0);
    }

    const size_t crow0 = (size_t)bm * 128 + wr * 64;
    const size_t ccol0 = (size_t)bn * 256 + wc * 64;
    #pragma unroll
    for (int m = 0; m < 4; ++m)
        #pragma unroll
        for (int n = 0; n < 4; ++n)
            #pragma unroll
            for (int r = 0; r < 4; ++r)
                C[(crow0 + m * 16 + g4 * 4 + r) * DD + ccol0 + n * 16 + r16] = acc[m][n][r];
}

// ---------------------------------------------------------------------------
// 3+4) Merged RoPE + V-transpose (independent regions of qkv; single launch).
//    bid < 6144: rope on row s = bid/3, col-group (bid%3)*256+tid (q scaled by
//    log2(e)/sqrt(HD)). bid >= 6144: 64x64 V-transpose tile into Vt.
// ---------------------------------------------------------------------------
__global__ __launch_bounds__(256) void rope_tv(unsigned short* __restrict__ qkv,
                                               const float* __restrict__ fc,
                                               const float* __restrict__ fs,
                                               unsigned short* __restrict__ Vt) {
    __shared__ unsigned short tile[64][72];
    const int bid = blockIdx.x;
    if (bid < 6144) {
        constexpr float QSCALE = 0.08838834764831845f * 1.4426950408889634f;
        const int g = (bid % 3) * 256 + threadIdx.x;   // 0..767, groups of 8 cols
        if (g >= 640) return;
        const int s = bid / 3;
        const int col = g * 8;
        unsigned short* p = qkv + (size_t)s * QKVW + col;
        u16x8 v = *reinterpret_cast<const u16x8*>(p);
        const int i0 = (col & 127) >> 1;
        f32x4 c  = *reinterpret_cast<const f32x4*>(fc + s * 64 + i0);
        f32x4 sn = *reinterpret_cast<const f32x4*>(fs + s * 64 + i0);
        const float post = (col < DD) ? QSCALE : 1.0f;
        u16x8 o;
        #pragma unroll
        for (int j = 0; j < 4; ++j) {
            float e  = b2f(v[2*j]);
            float od = b2f(v[2*j+1]);
            o[2*j]   = f2b((e * c[j] - od * sn[j]) * post);
            o[2*j+1] = f2b((e * sn[j] + od * c[j]) * post);
        }
        *reinterpret_cast<u16x8*>(p) = o;
    } else {
        const int t = bid - 6144;                      // 0..511
        const int d0g = (t & 15) * 64;
        const int s0  = (t >> 4) * 64;
        const int kvh = d0g >> 7, dl0 = d0g & 127;
        const int tid = threadIdx.x;
        #pragma unroll
        for (int p = 0; p < 2; ++p) {
            const int sgi = p * 256 + tid;
            const int srow = sgi >> 3, dseg = sgi & 7;
            u16x8 v = *reinterpret_cast<const u16x8*>(
                qkv + (size_t)(s0 + srow) * QKVW + 5120 + d0g + dseg * 8);
            #pragma unroll
            for (int j = 0; j < 8; ++j) tile[srow][dseg * 8 + j] = v[j];
        }
        __syncthreads();
        #pragma unroll
        for (int p = 0; p < 2; ++p) {
            const int sgi = p * 256 + tid;
            const int drow = sgi >> 3, sseg = sgi & 7;
            u16x8 v;
            #pragma unroll
            for (int j = 0; j < 8; ++j) v[j] = tile[sseg * 8 + j][drow];
            *reinterpret_cast<u16x8*>(
                Vt + (size_t)kvh * HD2 * S2 + (size_t)(dl0 + drow) * S2 + s0 + sseg * 8) = v;
        }
    }
}

// ---------------------------------------------------------------------------
// 5) Flash attention (r12 body) + wo fp32->bf16 conversion side-job.
//    attn runs at ~1.5% HBM utilization; each of the 256 blocks converts
//    256 KB of wo (4 batches x 8 f32x4/thread), loads issued one tile ahead,
//    converted+stored at tiles 1..4 (ntB >= 18). Per-tile WAITV(0) drain
//    makes the mixed vmcnt trivially safe. gemm_out (next kernel) reads wob.
// ---------------------------------------------------------------------------
__global__ __launch_bounds__(512) void attn_kernel(const unsigned short* __restrict__ Qkv,
                                                   const unsigned short* __restrict__ Vt,
                                                   unsigned short* __restrict__ O,
                                                   const float* __restrict__ wo_src,
                                                   unsigned short* __restrict__ wo_dst) {
    __shared__ unsigned short Klds[2][64 * 128];   // 32 KB
    __shared__ unsigned short Vlds[2][128 * 64];   // 32 KB
    __shared__ unsigned short Plds[8][2048];       // 32 KB (4 KB/wave, frag-ordered)

    const int kvh = blockIdx.x;                  // 0..7
    const int h   = kvh * 4 + (blockIdx.y & 3);
    const int p   = blockIdx.y >> 2;             // pair id 0..7
    const int cB  = 8 + p, cS = 7 - p;           // complement chunks
    const int w = threadIdx.x >> 6, lane = threadIdx.x & 63;
    const int tid = threadIdx.x;
    const int r16 = lane & 15, g4 = lane >> 4;

    const int myc = (w < 4) ? cB : cS;
    const int qw  = myc * 128 + (w & 3) * 32;    // wave's first q row
    const int ntB = 2 * cB + 2;                  // tiles staged by this block (>= 18)

    const unsigned short* Kbase = Qkv + DD + kvh * HD2;      // + kv*QKVW + d
    const unsigned short* Vtb   = Vt + (size_t)kvh * HD2 * S2;
    char* pw = (char*)(&Plds[w][0]);             // wave's 4KB P region

    // wo conversion side-job: block blk covers 16384 f32x4 groups
    const int blk = blockIdx.y * 8 + blockIdx.x;           // 0..255
    const f32x4* wo4 = (const f32x4*)wo_src;
    const int cb4 = blk * 16384 + tid;
    f32x4 cbuf[8];
    auto cvt_issue = [&](int k) {
        #pragma unroll
        for (int i = 0; i < 8; ++i)
            cbuf[i] = wo4[cb4 + k * 4096 + i * 512];
    };
    auto cvt_flush = [&](int k) {
        #pragma unroll
        for (int i = 0; i < 8; ++i) {
            u16x4 ov;
            ov[0] = f2b(cbuf[i][0]); ov[1] = f2b(cbuf[i][1]);
            ov[2] = f2b(cbuf[i][2]); ov[3] = f2b(cbuf[i][3]);
            *reinterpret_cast<u16x4*>(wo_dst + ((size_t)(cb4 + k * 4096 + i * 512)) * 4) = ov;
        }
    };

    // staging lane constants
    const int krow_l = lane >> 4;      // row within 4-row segment
    const int kchunk = lane & 15;      // 16B chunk within 256B K row
    const int vd_l   = lane >> 3;      // d within 8-row segment
    const int vchunk = lane & 7;       // 16B chunk within 128B V row

    // Q fragments (B-frag of swapped QK^T): rows qw+m*16+r16, d-slices f*32+g4*8
    bf16x8 qf[2][4];
    #pragma unroll
    for (int m = 0; m < 2; ++m)
        #pragma unroll
        for (int f = 0; f < 4; ++f)
            qf[m][f] = *reinterpret_cast<const bf16x8*>(
                Qkv + (size_t)(qw + m * 16 + r16) * QKVW + h * HD2 + f * 32 + g4 * 8);

    f32x4 o[2][8] = {};
    float mr[2] = {-3e38f, -3e38f};   // running max (log2 units) for q = m*16+r16
    float lr[2] = {0.f, 0.f};

    auto stage = [&](int buf, int kv0) {
        #pragma unroll
        for (int i = 0; i < 2; ++i) {
            const int seg = i * 8 + w;                     // 0..15
            const int row = seg * 4 + krow_l;              // kv row 0..63
            gload_lds16(Kbase + (size_t)(kv0 + row) * QKVW + ((kchunk ^ (row & 7)) * 8),
                        &Klds[buf][seg * 512]);
        }
        #pragma unroll
        for (int i = 0; i < 2; ++i) {
            const int seg = i * 8 + w;
            const int d = seg * 8 + vd_l;                  // d row 0..127
            gload_lds16(Vtb + (size_t)d * S2 + kv0 + ((vchunk ^ (d & 7)) * 8),
                        &Vlds[buf][seg * 512]);
        }
    };

    stage(0, 0);
    WAITV(0);
    __syncthreads();
    cvt_issue(0);                                 // overlaps tile 0 compute

    for (int t = 0; t < ntB; ++t) {
        if (t >= 1 && t <= 4) {                   // batch t-1 complete (drained at t-1 end)
            cvt_flush(t - 1);
            if (t < 4) cvt_issue(t);
        }
        const int buf = t & 1;
        const int kv0 = t * 64;
        if (t + 1 < ntB) stage(buf ^ 1, (t + 1) * 64);

        if (kv0 <= qw + 31) {                 // causal: this wave needs the tile
            // ---- QK^T swapped: sa[m][kb] = K_tile * Q^T -> C[kv][q] ----
            f32x4 sa[2][4] = {};
            #pragma unroll
            for (int kb = 0; kb < 4; ++kb) {
                bf16x8 kf[4];
                #pragma unroll
                for (int f = 0; f < 4; ++f)
                    kf[f] = *reinterpret_cast<const bf16x8*>(
                        &Klds[buf][(kb * 16 + r16) * 128 + (((f * 4 + g4) ^ (r16 & 7)) * 8)]);
                __builtin_amdgcn_s_setprio(1);
                #pragma unroll
                for (int m = 0; m < 2; ++m)
                    #pragma unroll
                    for (int f = 0; f < 4; ++f)
                        sa[m][kb] = __builtin_amdgcn_mfma_f32_16x16x32_bf16(
                            kf[f], qf[m][f], sa[m][kb], 0, 0, 0);
                __builtin_amdgcn_s_setprio(0);
            }
            // ---- causal mask: lane holds q = qw+m*16+r16, kv = kv0+kb*16+g4*4+r ----
            const bool needmask = (kv0 + 63 > qw);
            float sv[2][4][4];
            #pragma unroll
            for (int m = 0; m < 2; ++m)
                #pragma unroll
                for (int kb = 0; kb < 4; ++kb)
                    #pragma unroll
                    for (int r = 0; r < 4; ++r) {
                        float xx = sa[m][kb][r];
                        if (needmask) {
                            const int kvg = kv0 + kb * 16 + g4 * 4 + r;
                            const int qg  = qw + m * 16 + r16;
                            xx = (kvg > qg) ? -3e38f : xx;
                        }
                        sv[m][kb][r] = xx;
                    }
            // ---- per-q max: 15 in-lane ops + 2 shfl levels ----
            float rowm[2];
            #pragma unroll
            for (int m = 0; m < 2; ++m) {
                float a0 = fmaxf(fmaxf(sv[m][0][0], sv[m][0][1]), fmaxf(sv[m][0][2], sv[m][0][3]));
                float a1 = fmaxf(fmaxf(sv[m][1][0], sv[m][1][1]), fmaxf(sv[m][1][2], sv[m][1][3]));
                float a2 = fmaxf(fmaxf(sv[m][2][0], sv[m][2][1]), fmaxf(sv[m][2][2], sv[m][2][3]));
                float a3 = fmaxf(fmaxf(sv[m][3][0], sv[m][3][1]), fmaxf(sv[m][3][2], sv[m][3][3]));
                rowm[m] = fmaxf(fmaxf(a0, a1), fmaxf(a2, a3));
            }
            #pragma unroll
            for (int m = 0; m < 2; ++m) {
                rowm[m] = fmaxf(rowm[m], __shfl_xor(rowm[m], 16));
                rowm[m] = fmaxf(rowm[m], __shfl_xor(rowm[m], 32));
            }
            // ---- defer-max (T13, base-2 THR = 11.5 ~ e^8) ----
            const float gmax = fmaxf(rowm[0] - mr[0], rowm[1] - mr[1]);
            if (!__all(gmax <= 11.5f)) {
                float corr[2];
                #pragma unroll
                for (int m = 0; m < 2; ++m) {
                    const float mn = fmaxf(mr[m], rowm[m]);
                    corr[m] = exp2f(mr[m] - mn);
                    mr[m] = mn;
                    lr[m] *= corr[m];
                }
                #pragma unroll
                for (int m = 0; m < 2; ++m)
                    #pragma unroll
                    for (int r = 0; r < 4; ++r) {
                        const float co = __shfl(corr[m], (lane & 48) | (g4 * 4 + r));
                        #pragma unroll
                        for (int n = 0; n < 8; ++n) o[m][n][r] *= co;
                    }
            }
            // ---- P = exp2(S - m), row sums (in-lane + 2 shfl) ----
            float rs[2] = {0.f, 0.f};
            #pragma unroll
            for (int m = 0; m < 2; ++m)
                #pragma unroll
                for (int kb = 0; kb < 4; ++kb)
                    #pragma unroll
                    for (int r = 0; r < 4; ++r) {
                        const float pp = exp2f(sv[m][kb][r] - mr[m]);
                        sv[m][kb][r] = pp;
                        rs[m] += pp;
                    }
            #pragma unroll
            for (int m = 0; m < 2; ++m) {
                rs[m] += __shfl_xor(rs[m], 16);
                rs[m] += __shfl_xor(rs[m], 32);
                lr[m] += rs[m];
            }
            // ---- pack P pairs (cvt_pk) -> fragment-ordered Plds, 8 b64 writes ----
            #pragma unroll
            for (int m = 0; m < 2; ++m)
                #pragma unroll
                for (int kb = 0; kb < 4; ++kb) {
                    const unsigned w0 = cvt_pk_bf16(sv[m][kb][0], sv[m][kb][1]);
                    const unsigned w1 = cvt_pk_bf16(sv[m][kb][2], sv[m][kb][3]);
                    int wa = m * 2048 + ((kb * 2) + (g4 >> 1)) * 256 + r16 * 16 + (g4 & 1) * 8;
                    wa ^= (r16 >> 3) << 4;
                    *reinterpret_cast<unsigned long long*>(pw + wa) =
                        (unsigned long long)w0 | ((unsigned long long)w1 << 32);
                }
            asm volatile("s_waitcnt lgkmcnt(0)" ::: "memory");
            bf16x8 pa[2][2];
            #pragma unroll
            for (int m = 0; m < 2; ++m)
                #pragma unroll
                for (int kvs = 0; kvs < 2; ++kvs) {
                    int ra = m * 2048 + kvs * 1024 + lane * 16;
                    ra ^= (r16 >> 3) << 4;
                    pa[m][kvs] = *reinterpret_cast<const bf16x8*>(pw + ra);
                }
            // ---- PV: O[q][d] += P[q][kv] * Vt[d][kv] ----
            #pragma unroll
            for (int kvs = 0; kvs < 2; ++kvs)
                #pragma unroll
                for (int n = 0; n < 8; ++n) {
                    const bf16x8 vb = *reinterpret_cast<const bf16x8*>(
                        &Vlds[buf][(n * 16 + r16) * 64 + (((kvs * 4 + g4) ^ (r16 & 7)) * 8)]);
                    __builtin_amdgcn_s_setprio(1);
                    #pragma unroll
                    for (int m = 0; m < 2; ++m)
                        o[m][n] = __builtin_amdgcn_mfma_f32_16x16x32_bf16(
                            pa[m][kvs], vb, o[m][n], 0, 0, 0);
                    __builtin_amdgcn_s_setprio(0);
                }
        }

        WAITV(0);
        __syncthreads();
    }

    // ---- normalize (broadcast 1/lr to o-layout lanes) + write ----
    float inv[2];
    #pragma unroll
    for (int m = 0; m < 2; ++m) inv[m] = 1.0f / lr[m];
    #pragma unroll
    for (int m = 0; m < 2; ++m)
        #pragma unroll
        for (int r = 0; r < 4; ++r) {
            const float iv = __shfl(inv[m], (lane & 48) | (g4 * 4 + r));
            #pragma unroll
            for (int n = 0; n < 8; ++n)
                O[(size_t)(qw + m * 16 + g4 * 4 + r) * DD + h * HD2 + n * 16 + r16] =
                    f2b(o[m][n][r] * iv);
        }
}

// ---------------------------------------------------------------------------
extern "C" void kernel_launch(void* const* d_in, const int* in_sizes, int n_in,
                              void* d_out, int out_size, void* d_ws, size_t ws_size,
                              hipStream_t stream) {
    (void)in_sizes; (void)n_in; (void)out_size; (void)ws_size;
    const float* x  = (const float*)d_in[0];
    const float* wq = (const float*)d_in[1];
    const float* wk = (const float*)d_in[2];
    const float* wv = (const float*)d_in[3];
    const float* wo = (const float*)d_in[4];
    // d_in[5] = mask (causal tril; computed analytically in-kernel)
    const float* fc = (const float*)d_in[6];
    const float* fs = (const float*)d_in[7];
    float* out = (float*)d_out;

    unsigned short* ws = (unsigned short*)d_ws;
    const size_t M1 = 1024 * 1024;
    unsigned short* xb  = ws;              // 8M  (x bf16)
    unsigned short* wqb = ws + 8  * M1;    // 16M
    unsigned short* wkb = ws + 24 * M1;    // 4M
    unsigned short* wvb = ws + 28 * M1;    // 4M
    unsigned short* wob = ws + 32 * M1;    // 16M (written by attn side-job)
    unsigned short* qkv = ws + 48 * M1;    // 12M (S x 6144)
    unsigned short* vt  = ws + 60 * M1;    // 2M  (KVH x 128 x S)
    unsigned short* ob  = ws + 62 * M1;    // 8M  (S x 4096)

    cvt_all<<<2048, 256, 0, stream>>>(x, wq, wk, wv, ws);
    gemm_qkv<<<dim3(32, 8), 512, 0, stream>>>(xb, wqb, wkb, wvb, qkv);
    rope_tv<<<6656, 256, 0, stream>>>(qkv, fc, fs, vt);
    attn_kernel<<<dim3(8, 32), 512, 0, stream>>>(qkv, vt, ob, wo, wob);
    gemm_out<<<dim3(16, 16), 512, 0, stream>>>(ob, wob, out);
}

// Round 16
// 288.673 us; speedup vs baseline: 1.0456x; 1.0184x over previous
//
#include <hip/hip_runtime.h>
#include <hip/hip_bf16.h>
#include <stdint.h>

// Problem constants
#define S2   2048
#define DD   4096
#define NH   32
#define NKVH 8
#define HD2  128
// qkv buffer row width: 4096 (q) + 1024 (k) + 1024 (v)
#define QKVW 6144

typedef __bf16 bf16x8 __attribute__((ext_vector_type(8)));
typedef float  f32x4  __attribute__((ext_vector_type(4)));
typedef unsigned short u16x8 __attribute__((ext_vector_type(8)));
typedef unsigned short u16x4 __attribute__((ext_vector_type(4)));

__device__ __forceinline__ unsigned short f2b(float f) {
    unsigned int u = __builtin_bit_cast(unsigned int, f);
    unsigned int r = (u + 0x7FFFu + ((u >> 16) & 1u)) >> 16;   // RNE
    return (unsigned short)r;
}
__device__ __forceinline__ float b2f(unsigned short h) {
    unsigned int u = ((unsigned int)h) << 16;
    return __builtin_bit_cast(float, u);
}
__device__ __forceinline__ unsigned cvt_pk_bf16(float a, float b) {
    unsigned r;
    asm("v_cvt_pk_bf16_f32 %0, %1, %2" : "=v"(r) : "v"(a), "v"(b));
    return r;   // lo16 = bf16(a), hi16 = bf16(b)
}

// global -> LDS direct copy, 16B per lane. LDS dest is wave-uniform base + lane*16.
__device__ __forceinline__ void gload_lds16(const void* g, void* lds) {
    __builtin_amdgcn_global_load_lds(
        (const __attribute__((address_space(1))) void*)(uintptr_t)g,
        (__attribute__((address_space(3))) void*)(uint32_t)(uintptr_t)lds,
        16, 0, 0);
}

// raw barrier (no vmcnt drain) + compiler memory fences so LDS ops don't cross
#define BAR() do { asm volatile("" ::: "memory"); \
                   __builtin_amdgcn_s_barrier();  \
                   asm volatile("" ::: "memory"); } while (0)
#define WAITV(n) asm volatile("s_waitcnt vmcnt(" #n ")" ::: "memory")

template<int N> __device__ __forceinline__ void waitv() {
    if      constexpr (N == 0)  WAITV(0);
    else if constexpr (N == 1)  WAITV(1);
    else if constexpr (N == 2)  WAITV(2);
    else if constexpr (N == 3)  WAITV(3);
    else if constexpr (N == 4)  WAITV(4);
    else if constexpr (N == 5)  WAITV(5);
    else if constexpr (N == 6)  WAITV(6);
    else if constexpr (N == 8)  WAITV(8);
}

// ---------------------------------------------------------------------------
// 1) fp32 -> bf16 conversion for x, wq, wk, wv (wo is converted inside attn)
// ---------------------------------------------------------------------------
__global__ void cvt_all(const float* __restrict__ x,  const float* __restrict__ wq,
                        const float* __restrict__ wk, const float* __restrict__ wv,
                        unsigned short* __restrict__ dst) {
    const long long NG = 8LL * 1024 * 1024;   // float4 groups (x 2M | wq 4M | wk 1M | wv 1M)
    const long long stride = (long long)gridDim.x * blockDim.x;
    for (long long g = (long long)blockIdx.x * blockDim.x + threadIdx.x; g < NG; g += stride) {
        const float* src; long long off;
        if      (g < 2LL*1024*1024) { src = x;  off = g; }
        else if (g < 6LL*1024*1024) { src = wq; off = g - 2LL*1024*1024; }
        else if (g < 7LL*1024*1024) { src = wk; off = g - 6LL*1024*1024; }
        else                        { src = wv; off = g - 7LL*1024*1024; }
        f32x4 v = *reinterpret_cast<const f32x4*>(src + off * 4);
        u16x4 o;
        o[0] = f2b(v[0]); o[1] = f2b(v[1]); o[2] = f2b(v[2]); o[3] = f2b(v[3]);
        *reinterpret_cast<u16x4*>(dst + g * 4) = o;
    }
}

// ---------------------------------------------------------------------------
// 2) QKV GEMM  qkv[2048 x 6144] = x * [wq|wk|wv]^T.  (r12, unchanged)
//    BM=256, BN=192, BK=64 -> grid (32,8) = 256 blocks. 8 waves 4M x 2N.
// ---------------------------------------------------------------------------
__global__ __launch_bounds__(512) void gemm_qkv(
    const unsigned short* __restrict__ A,    // xb  [2048 x 4096]
    const unsigned short* __restrict__ B0,   // wq  [4096 x 4096]
    const unsigned short* __restrict__ B1,   // wk  [1024 x 4096]
    const unsigned short* __restrict__ B2,   // wv  [1024 x 4096]
    unsigned short* __restrict__ C)          // qkv [2048 x 6144]
{
    constexpr int K = 4096, BK = 64, NT = K / BK;
    __shared__ unsigned short As[2][256 * 64];   // 64 KB
    __shared__ unsigned short Bs[2][192 * 64];   // 48 KB

    const int bm = blockIdx.y, bn = blockIdx.x;  // (32, 8): lin%8 == bn%8
    const int tid = threadIdx.x;
    const int w = tid >> 6, lane = tid & 63;
    const int wr = w >> 1, wc = w & 1;           // 4M x 2N
    const int r16 = lane & 15, g4 = lane >> 4;

    const int bn0 = bn * 192;
    const unsigned short* Ap = A + (size_t)bm * 256 * K;

    const int lrow = lane >> 3;   // 0..7 (row within 8-row unit)
    const int lchk = lane & 7;    // 0..7 (16B chunk within 128B row)

    f32x4 acc[4][6] = {};
    bf16x8 af[2][2], b0[3][2], b1[3][2];

    auto browbase = [&](int rowg) -> const unsigned short* {
        if (rowg < 4096) return B0 + (size_t)rowg * K;
        if (rowg < 5120) return B1 + (size_t)(rowg - 4096) * K;
        return B2 + (size_t)(rowg - 5120) * K;
    };

    auto stageA = [&](int buf, int tt, int half) {
        #pragma unroll
        for (int i = 0; i < 2; ++i) {
            const int j = i * 8 + w;                               // unit 0..15
            const int row0 = (j >> 2) * 64 + half * 32 + (j & 3) * 8;
            const int row = row0 + lrow;
            gload_lds16(Ap + (size_t)row * K + tt * BK + ((lchk ^ (row & 7)) * 8),
                        &As[buf][row0 * 64]);
        }
    };
    auto stageB = [&](int buf, int tt, int half) {
        #pragma unroll
        for (int i = 0; i < 2; ++i) {
            const int j = (i == 0) ? w : (8 + (w & 3));            // unit 0..11
            const int row0 = (j < 6) ? (half * 48 + j * 8)
                                     : (96 + half * 48 + (j - 6) * 8);
            const int row = row0 + lrow;
            const unsigned short* src = browbase(bn0 + row0) + (size_t)lrow * K;
            gload_lds16(src + tt * BK + ((lchk ^ (row & 7)) * 8),
                        &Bs[buf][row0 * 64]);
        }
    };
    auto readA = [&](int buf, int mh) {
        #pragma unroll
        for (int m = 0; m < 2; ++m)
            #pragma unroll
            for (int kk = 0; kk < 2; ++kk) {
                const int row = wr * 64 + mh * 32 + m * 16 + r16;
                af[m][kk] = *reinterpret_cast<const bf16x8*>(
                    &As[buf][row * 64 + (((kk * 4 + g4) ^ (row & 7)) * 8)]);
            }
    };
    auto readB = [&](int buf, int nh, bf16x8 (&br)[3][2]) {
        #pragma unroll
        for (int n = 0; n < 3; ++n)
            #pragma unroll
            for (int kk = 0; kk < 2; ++kk) {
                const int row = wc * 96 + nh * 48 + n * 16 + r16;
                br[n][kk] = *reinterpret_cast<const bf16x8*>(
                    &Bs[buf][row * 64 + (((kk * 4 + g4) ^ (row & 7)) * 8)]);
            }
    };
    auto mma = [&](bf16x8 (&br)[3][2], int mh, int nh) {
        __builtin_amdgcn_s_setprio(1);
        #pragma unroll
        for (int m = 0; m < 2; ++m)
            #pragma unroll
            for (int n = 0; n < 3; ++n)
                #pragma unroll
                for (int kk = 0; kk < 2; ++kk)
                    acc[mh * 2 + m][nh * 3 + n] = __builtin_amdgcn_mfma_f32_16x16x32_bf16(
                        af[m][kk], br[n][kk], acc[mh * 2 + m][nh * 3 + n], 0, 0, 0);
        __builtin_amdgcn_s_setprio(0);
    };

    // prologue (consumption order); leaves B-h1, A-h1 in flight = 4
    stageA(0, 0, 0); stageB(0, 0, 0); stageB(0, 0, 1); stageA(0, 0, 1);
    waitv<4>();
    BAR();

    for (int t = 0; t < NT - 1; ++t) {
        const int buf = t & 1;
        // ---- phase 0: Q(0,0) ----
        readA(buf, 0); readB(buf, 0, b0);
        stageA(buf ^ 1, t + 1, 0); stageB(buf ^ 1, t + 1, 0);
        BAR();
        mma(b0, 0, 0);
        waitv<6>();                 // 2LA+LB: B-h1(t) landed
        BAR();
        // ---- phase 1: Q(0,1) ----
        readB(buf, 1, b1);
        stageB(buf ^ 1, t + 1, 1);
        BAR();
        mma(b1, 0, 1);
        waitv<6>();                 // LA+2LB: A-h1(t) landed
        BAR();
        // ---- phase 2: Q(1,1) ----
        readA(buf, 1);
        stageA(buf ^ 1, t + 1, 1);
        BAR();
        mma(b1, 1, 1);
        BAR();
        // ---- phase 3: Q(1,0) ----
        mma(b0, 1, 0);
        waitv<4>();                 // LA+LB: A-h0(t+1), B-h0(t+1) landed
        BAR();
    }
    // ---- last tile (no staging; peeled vmcnt) ----
    {
        const int buf = (NT - 1) & 1;
        readA(buf, 0); readB(buf, 0, b0);
        BAR();
        mma(b0, 0, 0);
        waitv<2>();
        BAR();
        readB(buf, 1, b1);
        mma(b1, 0, 1);
        waitv<0>();
        readA(buf, 1);
        mma(b1, 1, 1);
        mma(b0, 1, 0);
    }

    // ---- epilogue ----
    const size_t crow0 = (size_t)bm * 256 + wr * 64;
    const size_t ccol0 = (size_t)bn0 + wc * 96;
    #pragma unroll
    for (int m = 0; m < 4; ++m)
        #pragma unroll
        for (int n = 0; n < 6; ++n)
            #pragma unroll
            for (int r = 0; r < 4; ++r)
                C[(crow0 + m * 16 + g4 * 4 + r) * QKVW + ccol0 + n * 16 + r16] =
                    f2b(acc[m][n][r]);
}

// ---------------------------------------------------------------------------
// 2b) O-proj GEMM  out[2048 x 4096] = ob * wo^T.  (unchanged from r9)
//     BM=128, BN=256, BK=64 -> grid (16,16) = 256 blocks. 8 waves 2M x 4N.
// ---------------------------------------------------------------------------
__global__ __launch_bounds__(512) void gemm_out(
    const unsigned short* __restrict__ A,   // ob  [2048 x 4096] bf16
    const unsigned short* __restrict__ B,   // wob [4096 x 4096] bf16
    float* __restrict__ C)                  // out [2048 x 4096] f32
{
    constexpr int K = 4096, BK = 64, NT = K / BK;
    __shared__ unsigned short As[2][128 * 64];   // 32 KB
    __shared__ unsigned short Bs[2][256 * 64];   // 64 KB

    const int bm = blockIdx.y, bn = blockIdx.x;  // (16, 16): lin%8 == bn%8
    const int tid = threadIdx.x;
    const int w = tid >> 6, lane = tid & 63;
    const int wr = w >> 2, wc = w & 3;           // 2M x 4N
    const int r16 = lane & 15, g4 = lane >> 4;

    const unsigned short* Ap = A + (size_t)bm * 128 * K;
    const unsigned short* Bp = B + (size_t)bn * 256 * K;

    const int lrow = lane >> 3;
    const int lchk = lane & 7;

    f32x4 acc[4][4] = {};
    bf16x8 af[2][2], b0[2][2], b1[2][2];

    auto stageA = [&](int buf, int tt, int half) {
        const int j = w;                                           // unit 0..7
        const int row0 = (j >> 2) * 64 + half * 32 + (j & 3) * 8;
        const int row = row0 + lrow;
        gload_lds16(Ap + (size_t)row * K + tt * BK + ((lchk ^ (row & 7)) * 8),
                    &As[buf][row0 * 64]);
    };
    auto stageB = [&](int buf, int tt, int half) {
        #pragma unroll
        for (int i = 0; i < 2; ++i) {
            const int j = i * 8 + w;                               // unit 0..15
            const int row0 = (j >> 2) * 64 + half * 32 + (j & 3) * 8;
            const int row = row0 + lrow;
            gload_lds16(Bp + (size_t)row * K + tt * BK + ((lchk ^ (row & 7)) * 8),
                        &Bs[buf][row0 * 64]);
        }
    };
    auto readA = [&](int buf, int mh) {
        #pragma unroll
        for (int m = 0; m < 2; ++m)
            #pragma unroll
            for (int kk = 0; kk < 2; ++kk) {
                const int row = wr * 64 + mh * 32 + m * 16 + r16;
                af[m][kk] = *reinterpret_cast<const bf16x8*>(
                    &As[buf][row * 64 + (((kk * 4 + g4) ^ (row & 7)) * 8)]);
            }
    };
    auto readB = [&](int buf, int nh, bf16x8 (&br)[2][2]) {
        #pragma unroll
        for (int n = 0; n < 2; ++n)
            #pragma unroll
            for (int kk = 0; kk < 2; ++kk) {
                const int row = wc * 64 + nh * 32 + n * 16 + r16;
                br[n][kk] = *reinterpret_cast<const bf16x8*>(
                    &Bs[buf][row * 64 + (((kk * 4 + g4) ^ (row & 7)) * 8)]);
            }
    };
    auto mma = [&](bf16x8 (&br)[2][2], int mh, int nh) {
        __builtin_amdgcn_s_setprio(1);
        #pragma unroll
        for (int m = 0; m < 2; ++m)
            #pragma unroll
            for (int n = 0; n < 2; ++n)
                #pragma unroll
                for (int kk = 0; kk < 2; ++kk)
                    acc[mh * 2 + m][nh * 2 + n] = __builtin_amdgcn_mfma_f32_16x16x32_bf16(
                        af[m][kk], br[n][kk], acc[mh * 2 + m][nh * 2 + n], 0, 0, 0);
        __builtin_amdgcn_s_setprio(0);
    };

    stageA(0, 0, 0); stageB(0, 0, 0); stageB(0, 0, 1); stageA(0, 0, 1);
    waitv<3>();                     // LA+LB
    BAR();

    for (int t = 0; t < NT - 1; ++t) {
        const int buf = t & 1;
        readA(buf, 0); readB(buf, 0, b0);
        stageA(buf ^ 1, t + 1, 0); stageB(buf ^ 1, t + 1, 0);
        BAR();
        mma(b0, 0, 0);
        waitv<4>();                 // 2LA+LB
        BAR();
        readB(buf, 1, b1);
        stageB(buf ^ 1, t + 1, 1);
        BAR();
        mma(b1, 0, 1);
        waitv<5>();                 // LA+2LB
        BAR();
        readA(buf, 1);
        stageA(buf ^ 1, t + 1, 1);
        BAR();
        mma(b1, 1, 1);
        BAR();
        mma(b0, 1, 0);
        waitv<3>();                 // LA+LB
        BAR();
    }
    {
        const int buf = (NT - 1) & 1;
        readA(buf, 0); readB(buf, 0, b0);
        BAR();
        mma(b0, 0, 0);
        waitv<1>();
        BAR();
        readB(buf, 1, b1);
        mma(b1, 0, 1);
        waitv<0>();
        readA(buf, 1);
        mma(b1, 1, 1);
        mma(b0, 1, 0);
    }

    const size_t crow0 = (size_t)bm * 128 + wr * 64;
    const size_t ccol0 = (size_t)bn * 256 + wc * 64;
    #pragma unroll
    for (int m = 0; m < 4; ++m)
        #pragma unroll
        for (int n = 0; n < 4; ++n)
            #pragma unroll
            for (int r = 0; r < 4; ++r)
                C[(crow0 + m * 16 + g4 * 4 + r) * DD + ccol0 + n * 16 + r16] = acc[m][n][r];
}

// ---------------------------------------------------------------------------
// 3+4) Merged RoPE + V-transpose (independent regions of qkv; single launch).
// ---------------------------------------------------------------------------
__global__ __launch_bounds__(256) void rope_tv(unsigned short* __restrict__ qkv,
                                               const float* __restrict__ fc,
                                               const float* __restrict__ fs,
                                               unsigned short* __restrict__ Vt) {
    __shared__ unsigned short tile[64][72];
    const int bid = blockIdx.x;
    if (bid < 6144) {
        constexpr float QSCALE = 0.08838834764831845f * 1.4426950408889634f;
        const int g = (bid % 3) * 256 + threadIdx.x;   // 0..767, groups of 8 cols
        if (g >= 640) return;
        const int s = bid / 3;
        const int col = g * 8;
        unsigned short* p = qkv + (size_t)s * QKVW + col;
        u16x8 v = *reinterpret_cast<const u16x8*>(p);
        const int i0 = (col & 127) >> 1;
        f32x4 c  = *reinterpret_cast<const f32x4*>(fc + s * 64 + i0);
        f32x4 sn = *reinterpret_cast<const f32x4*>(fs + s * 64 + i0);
        const float post = (col < DD) ? QSCALE : 1.0f;
        u16x8 o;
        #pragma unroll
        for (int j = 0; j < 4; ++j) {
            float e  = b2f(v[2*j]);
            float od = b2f(v[2*j+1]);
            o[2*j]   = f2b((e * c[j] - od * sn[j]) * post);
            o[2*j+1] = f2b((e * sn[j] + od * c[j]) * post);
        }
        *reinterpret_cast<u16x8*>(p) = o;
    } else {
        const int t = bid - 6144;                      // 0..511
        const int d0g = (t & 15) * 64;
        const int s0  = (t >> 4) * 64;
        const int kvh = d0g >> 7, dl0 = d0g & 127;
        const int tid = threadIdx.x;
        #pragma unroll
        for (int p = 0; p < 2; ++p) {
            const int sgi = p * 256 + tid;
            const int srow = sgi >> 3, dseg = sgi & 7;
            u16x8 v = *reinterpret_cast<const u16x8*>(
                qkv + (size_t)(s0 + srow) * QKVW + 5120 + d0g + dseg * 8);
            #pragma unroll
            for (int j = 0; j < 8; ++j) tile[srow][dseg * 8 + j] = v[j];
        }
        __syncthreads();
        #pragma unroll
        for (int p = 0; p < 2; ++p) {
            const int sgi = p * 256 + tid;
            const int drow = sgi >> 3, sseg = sgi & 7;
            u16x8 v;
            #pragma unroll
            for (int j = 0; j < 8; ++j) v[j] = tile[sseg * 8 + j][drow];
            *reinterpret_cast<u16x8*>(
                Vt + (size_t)kvh * HD2 * S2 + (size_t)(dl0 + drow) * S2 + s0 + sseg * 8) = v;
        }
    }
}

// ---------------------------------------------------------------------------
// 5) Flash attention (r12 body) + wo fp32->bf16 side-job, spread thin.
//    r15 lesson: 4 batches x 8 f32x4 over tiles 1..4 demanded ~11 TB/s and
//    stretched the early tiles (+31 us). Now 16 batches x 2 f32x4 over tiles
//    1..16: per-tile added traffic 6 MB / ~2.2 us = ~2.7 TB/s, under the HBM
//    ceiling -> fully hidden under compute. All blocks have ntB >= 18.
// ---------------------------------------------------------------------------
__global__ __launch_bounds__(512) void attn_kernel(const unsigned short* __restrict__ Qkv,
                                                   const unsigned short* __restrict__ Vt,
                                                   unsigned short* __restrict__ O,
                                                   const float* __restrict__ wo_src,
                                                   unsigned short* __restrict__ wo_dst) {
    __shared__ unsigned short Klds[2][64 * 128];   // 32 KB
    __shared__ unsigned short Vlds[2][128 * 64];   // 32 KB
    __shared__ unsigned short Plds[8][2048];       // 32 KB (4 KB/wave, frag-ordered)

    const int kvh = blockIdx.x;                  // 0..7
    const int h   = kvh * 4 + (blockIdx.y & 3);
    const int p   = blockIdx.y >> 2;             // pair id 0..7
    const int cB  = 8 + p, cS = 7 - p;           // complement chunks
    const int w = threadIdx.x >> 6, lane = threadIdx.x & 63;
    const int tid = threadIdx.x;
    const int r16 = lane & 15, g4 = lane >> 4;

    const int myc = (w < 4) ? cB : cS;
    const int qw  = myc * 128 + (w & 3) * 32;    // wave's first q row
    const int ntB = 2 * cB + 2;                  // tiles staged by this block (>= 18)

    const unsigned short* Kbase = Qkv + DD + kvh * HD2;      // + kv*QKVW + d
    const unsigned short* Vtb   = Vt + (size_t)kvh * HD2 * S2;
    char* pw = (char*)(&Plds[w][0]);             // wave's 4KB P region

    // wo conversion side-job: block blk covers 16384 f32x4 groups,
    // 16 batches x (2 f32x4 per thread), issue at tile k, flush at k+1.
    const int blk = blockIdx.y * 8 + blockIdx.x;           // 0..255
    const f32x4* wo4 = (const f32x4*)wo_src;
    const int cb4 = blk * 16384 + tid;
    f32x4 cbuf[2];
    auto cvt_issue = [&](int k) {
        #pragma unroll
        for (int i = 0; i < 2; ++i)
            cbuf[i] = wo4[cb4 + k * 1024 + i * 512];
    };
    auto cvt_flush = [&](int k) {
        #pragma unroll
        for (int i = 0; i < 2; ++i) {
            u16x4 ov;
            ov[0] = f2b(cbuf[i][0]); ov[1] = f2b(cbuf[i][1]);
            ov[2] = f2b(cbuf[i][2]); ov[3] = f2b(cbuf[i][3]);
            *reinterpret_cast<u16x4*>(wo_dst + ((size_t)(cb4 + k * 1024 + i * 512)) * 4) = ov;
        }
    };

    // staging lane constants
    const int krow_l = lane >> 4;      // row within 4-row segment
    const int kchunk = lane & 15;      // 16B chunk within 256B K row
    const int vd_l   = lane >> 3;      // d within 8-row segment
    const int vchunk = lane & 7;       // 16B chunk within 128B V row

    // Q fragments (B-frag of swapped QK^T): rows qw+m*16+r16, d-slices f*32+g4*8
    bf16x8 qf[2][4];
    #pragma unroll
    for (int m = 0; m < 2; ++m)
        #pragma unroll
        for (int f = 0; f < 4; ++f)
            qf[m][f] = *reinterpret_cast<const bf16x8*>(
                Qkv + (size_t)(qw + m * 16 + r16) * QKVW + h * HD2 + f * 32 + g4 * 8);

    f32x4 o[2][8] = {};
    float mr[2] = {-3e38f, -3e38f};   // running max (log2 units) for q = m*16+r16
    float lr[2] = {0.f, 0.f};

    auto stage = [&](int buf, int kv0) {
        #pragma unroll
        for (int i = 0; i < 2; ++i) {
            const int seg = i * 8 + w;                     // 0..15
            const int row = seg * 4 + krow_l;              // kv row 0..63
            gload_lds16(Kbase + (size_t)(kv0 + row) * QKVW + ((kchunk ^ (row & 7)) * 8),
                        &Klds[buf][seg * 512]);
        }
        #pragma unroll
        for (int i = 0; i < 2; ++i) {
            const int seg = i * 8 + w;
            const int d = seg * 8 + vd_l;                  // d row 0..127
            gload_lds16(Vtb + (size_t)d * S2 + kv0 + ((vchunk ^ (d & 7)) * 8),
                        &Vlds[buf][seg * 512]);
        }
    };

    stage(0, 0);
    WAITV(0);
    __syncthreads();
    cvt_issue(0);                                 // overlaps tile 0 compute

    for (int t = 0; t < ntB; ++t) {
        if (t >= 1 && t <= 16) {                  // batch t-1 drained at tile t-1 end
            cvt_flush(t - 1);
            if (t < 16) cvt_issue(t);
        }
        const int buf = t & 1;
        const int kv0 = t * 64;
        if (t + 1 < ntB) stage(buf ^ 1, (t + 1) * 64);

        if (kv0 <= qw + 31) {                 // causal: this wave needs the tile
            // ---- QK^T swapped: sa[m][kb] = K_tile * Q^T -> C[kv][q] ----
            f32x4 sa[2][4] = {};
            #pragma unroll
            for (int kb = 0; kb < 4; ++kb) {
                bf16x8 kf[4];
                #pragma unroll
                for (int f = 0; f < 4; ++f)
                    kf[f] = *reinterpret_cast<const bf16x8*>(
                        &Klds[buf][(kb * 16 + r16) * 128 + (((f * 4 + g4) ^ (r16 & 7)) * 8)]);
                __builtin_amdgcn_s_setprio(1);
                #pragma unroll
                for (int m = 0; m < 2; ++m)
                    #pragma unroll
                    for (int f = 0; f < 4; ++f)
                        sa[m][kb] = __builtin_amdgcn_mfma_f32_16x16x32_bf16(
                            kf[f], qf[m][f], sa[m][kb], 0, 0, 0);
                __builtin_amdgcn_s_setprio(0);
            }
            // ---- causal mask: lane holds q = qw+m*16+r16, kv = kv0+kb*16+g4*4+r ----
            const bool needmask = (kv0 + 63 > qw);
            float sv[2][4][4];
            #pragma unroll
            for (int m = 0; m < 2; ++m)
                #pragma unroll
                for (int kb = 0; kb < 4; ++kb)
                    #pragma unroll
                    for (int r = 0; r < 4; ++r) {
                        float xx = sa[m][kb][r];
                        if (needmask) {
                            const int kvg = kv0 + kb * 16 + g4 * 4 + r;
                            const int qg  = qw + m * 16 + r16;
                            xx = (kvg > qg) ? -3e38f : xx;
                        }
                        sv[m][kb][r] = xx;
                    }
            // ---- per-q max: 15 in-lane ops + 2 shfl levels ----
            float rowm[2];
            #pragma unroll
            for (int m = 0; m < 2; ++m) {
                float a0 = fmaxf(fmaxf(sv[m][0][0], sv[m][0][1]), fmaxf(sv[m][0][2], sv[m][0][3]));
                float a1 = fmaxf(fmaxf(sv[m][1][0], sv[m][1][1]), fmaxf(sv[m][1][2], sv[m][1][3]));
                float a2 = fmaxf(fmaxf(sv[m][2][0], sv[m][2][1]), fmaxf(sv[m][2][2], sv[m][2][3]));
                float a3 = fmaxf(fmaxf(sv[m][3][0], sv[m][3][1]), fmaxf(sv[m][3][2], sv[m][3][3]));
                rowm[m] = fmaxf(fmaxf(a0, a1), fmaxf(a2, a3));
            }
            #pragma unroll
            for (int m = 0; m < 2; ++m) {
                rowm[m] = fmaxf(rowm[m], __shfl_xor(rowm[m], 16));
                rowm[m] = fmaxf(rowm[m], __shfl_xor(rowm[m], 32));
            }
            // ---- defer-max (T13, base-2 THR = 11.5 ~ e^8) ----
            const float gmax = fmaxf(rowm[0] - mr[0], rowm[1] - mr[1]);
            if (!__all(gmax <= 11.5f)) {
                float corr[2];
                #pragma unroll
                for (int m = 0; m < 2; ++m) {
                    const float mn = fmaxf(mr[m], rowm[m]);
                    corr[m] = exp2f(mr[m] - mn);
                    mr[m] = mn;
                    lr[m] *= corr[m];
                }
                #pragma unroll
                for (int m = 0; m < 2; ++m)
                    #pragma unroll
                    for (int r = 0; r < 4; ++r) {
                        const float co = __shfl(corr[m], (lane & 48) | (g4 * 4 + r));
                        #pragma unroll
                        for (int n = 0; n < 8; ++n) o[m][n][r] *= co;
                    }
            }
            // ---- P = exp2(S - m), row sums (in-lane + 2 shfl) ----
            float rs[2] = {0.f, 0.f};
            #pragma unroll
            for (int m = 0; m < 2; ++m)
                #pragma unroll
                for (int kb = 0; kb < 4; ++kb)
                    #pragma unroll
                    for (int r = 0; r < 4; ++r) {
                        const float pp = exp2f(sv[m][kb][r] - mr[m]);
                        sv[m][kb][r] = pp;
                        rs[m] += pp;
                    }
            #pragma unroll
            for (int m = 0; m < 2; ++m) {
                rs[m] += __shfl_xor(rs[m], 16);
                rs[m] += __shfl_xor(rs[m], 32);
                lr[m] += rs[m];
            }
            // ---- pack P pairs (cvt_pk) -> fragment-ordered Plds, 8 b64 writes ----
            #pragma unroll
            for (int m = 0; m < 2; ++m)
                #pragma unroll
                for (int kb = 0; kb < 4; ++kb) {
                    const unsigned w0 = cvt_pk_bf16(sv[m][kb][0], sv[m][kb][1]);
                    const unsigned w1 = cvt_pk_bf16(sv[m][kb][2], sv[m][kb][3]);
                    int wa = m * 2048 + ((kb * 2) + (g4 >> 1)) * 256 + r16 * 16 + (g4 & 1) * 8;
                    wa ^= (r16 >> 3) << 4;
                    *reinterpret_cast<unsigned long long*>(pw + wa) =
                        (unsigned long long)w0 | ((unsigned long long)w1 << 32);
                }
            asm volatile("s_waitcnt lgkmcnt(0)" ::: "memory");
            bf16x8 pa[2][2];
            #pragma unroll
            for (int m = 0; m < 2; ++m)
                #pragma unroll
                for (int kvs = 0; kvs < 2; ++kvs) {
                    int ra = m * 2048 + kvs * 1024 + lane * 16;
                    ra ^= (r16 >> 3) << 4;
                    pa[m][kvs] = *reinterpret_cast<const bf16x8*>(pw + ra);
                }
            // ---- PV: O[q][d] += P[q][kv] * Vt[d][kv] ----
            #pragma unroll
            for (int kvs = 0; kvs < 2; ++kvs)
                #pragma unroll
                for (int n = 0; n < 8; ++n) {
                    const bf16x8 vb = *reinterpret_cast<const bf16x8*>(
                        &Vlds[buf][(n * 16 + r16) * 64 + (((kvs * 4 + g4) ^ (r16 & 7)) * 8)]);
                    __builtin_amdgcn_s_setprio(1);
                    #pragma unroll
                    for (int m = 0; m < 2; ++m)
                        o[m][n] = __builtin_amdgcn_mfma_f32_16x16x32_bf16(
                            pa[m][kvs], vb, o[m][n], 0, 0, 0);
                    __builtin_amdgcn_s_setprio(0);
                }
        }

        WAITV(0);
        __syncthreads();
    }

    // ---- normalize (broadcast 1/lr to o-layout lanes) + write ----
    float inv[2];
    #pragma unroll
    for (int m = 0; m < 2; ++m) inv[m] = 1.0f / lr[m];
    #pragma unroll
    for (int m = 0; m < 2; ++m)
        #pragma unroll
        for (int r = 0; r < 4; ++r) {
            const float iv = __shfl(inv[m], (lane & 48) | (g4 * 4 + r));
            #pragma unroll
            for (int n = 0; n < 8; ++n)
                O[(size_t)(qw + m * 16 + g4 * 4 + r) * DD + h * HD2 + n * 16 + r16] =
                    f2b(o[m][n][r] * iv);
        }
}

// ---------------------------------------------------------------------------
extern "C" void kernel_launch(void* const* d_in, const int* in_sizes, int n_in,
                              void* d_out, int out_size, void* d_ws, size_t ws_size,
                              hipStream_t stream) {
    (void)in_sizes; (void)n_in; (void)out_size; (void)ws_size;
    const float* x  = (const float*)d_in[0];
    const float* wq = (const float*)d_in[1];
    const float* wk = (const float*)d_in[2];
    const float* wv = (const float*)d_in[3];
    const float* wo = (const float*)d_in[4];
    // d_in[5] = mask (causal tril; computed analytically in-kernel)
    const float* fc = (const float*)d_in[6];
    const float* fs = (const float*)d_in[7];
    float* out = (float*)d_out;

    unsigned short* ws = (unsigned short*)d_ws;
    const size_t M1 = 1024 * 1024;
    unsigned short* xb  = ws;              // 8M  (x bf16)
    unsigned short* wqb = ws + 8  * M1;    // 16M
    unsigned short* wkb = ws + 24 * M1;    // 4M
    unsigned short* wvb = ws + 28 * M1;    // 4M
    unsigned short* wob = ws + 32 * M1;    // 16M (written by attn side-job)
    unsigned short* qkv = ws + 48 * M1;    // 12M (S x 6144)
    unsigned short* vt  = ws + 60 * M1;    // 2M  (KVH x 128 x S)
    unsigned short* ob  = ws + 62 * M1;    // 8M  (S x 4096)

    cvt_all<<<2048, 256, 0, stream>>>(x, wq, wk, wv, ws);
    gemm_qkv<<<dim3(32, 8), 512, 0, stream>>>(xb, wqb, wkb, wvb, qkv);
    rope_tv<<<6656, 256, 0, stream>>>(qkv, fc, fs, vt);
    attn_kernel<<<dim3(8, 32), 512, 0, stream>>>(qkv, vt, ob, wo, wob);
    gemm_out<<<dim3(16, 16), 512, 0, stream>>>(ob, wob, out);
}

// Round 17
// 281.985 us; speedup vs baseline: 1.0704x; 1.0237x over previous
//
#include <hip/hip_runtime.h>
#include <hip/hip_bf16.h>
#include <stdint.h>

// Problem constants
#define S2   2048
#define DD   4096
#define NH   32
#define NKVH 8
#define HD2  128
// qkv buffer row width: 4096 (q) + 1024 (k) + 1024 (v)
#define QKVW 6144

typedef __bf16 bf16x8 __attribute__((ext_vector_type(8)));
typedef float  f32x4  __attribute__((ext_vector_type(4)));
typedef unsigned short u16x8 __attribute__((ext_vector_type(8)));
typedef unsigned short u16x4 __attribute__((ext_vector_type(4)));

__device__ __forceinline__ unsigned short f2b(float f) {
    unsigned int u = __builtin_bit_cast(unsigned int, f);
    unsigned int r = (u + 0x7FFFu + ((u >> 16) & 1u)) >> 16;   // RNE
    return (unsigned short)r;
}
__device__ __forceinline__ float b2f(unsigned short h) {
    unsigned int u = ((unsigned int)h) << 16;
    return __builtin_bit_cast(float, u);
}
__device__ __forceinline__ unsigned cvt_pk_bf16(float a, float b) {
    unsigned r;
    asm("v_cvt_pk_bf16_f32 %0, %1, %2" : "=v"(r) : "v"(a), "v"(b));
    return r;   // lo16 = bf16(a), hi16 = bf16(b)
}

// global -> LDS direct copy, 16B per lane. LDS dest is wave-uniform base + lane*16.
__device__ __forceinline__ void gload_lds16(const void* g, void* lds) {
    __builtin_amdgcn_global_load_lds(
        (const __attribute__((address_space(1))) void*)(uintptr_t)g,
        (__attribute__((address_space(3))) void*)(uint32_t)(uintptr_t)lds,
        16, 0, 0);
}

// raw barrier (no vmcnt drain) + compiler memory fences so LDS ops don't cross
#define BAR() do { asm volatile("" ::: "memory"); \
                   __builtin_amdgcn_s_barrier();  \
                   asm volatile("" ::: "memory"); } while (0)
#define WAITV(n) asm volatile("s_waitcnt vmcnt(" #n ")" ::: "memory")

template<int N> __device__ __forceinline__ void waitv() {
    if      constexpr (N == 0)  WAITV(0);
    else if constexpr (N == 1)  WAITV(1);
    else if constexpr (N == 2)  WAITV(2);
    else if constexpr (N == 3)  WAITV(3);
    else if constexpr (N == 4)  WAITV(4);
    else if constexpr (N == 5)  WAITV(5);
    else if constexpr (N == 6)  WAITV(6);
    else if constexpr (N == 8)  WAITV(8);
}

// ---------------------------------------------------------------------------
// 1) fp32 -> bf16 conversion for x, wq, wk, wv (wo is converted inside attn)
// ---------------------------------------------------------------------------
__global__ void cvt_all(const float* __restrict__ x,  const float* __restrict__ wq,
                        const float* __restrict__ wk, const float* __restrict__ wv,
                        unsigned short* __restrict__ dst) {
    const long long NG = 8LL * 1024 * 1024;   // float4 groups (x 2M | wq 4M | wk 1M | wv 1M)
    const long long stride = (long long)gridDim.x * blockDim.x;
    for (long long g = (long long)blockIdx.x * blockDim.x + threadIdx.x; g < NG; g += stride) {
        const float* src; long long off;
        if      (g < 2LL*1024*1024) { src = x;  off = g; }
        else if (g < 6LL*1024*1024) { src = wq; off = g - 2LL*1024*1024; }
        else if (g < 7LL*1024*1024) { src = wk; off = g - 6LL*1024*1024; }
        else                        { src = wv; off = g - 7LL*1024*1024; }
        f32x4 v = *reinterpret_cast<const f32x4*>(src + off * 4);
        u16x4 o;
        o[0] = f2b(v[0]); o[1] = f2b(v[1]); o[2] = f2b(v[2]); o[3] = f2b(v[3]);
        *reinterpret_cast<u16x4*>(dst + g * 4) = o;
    }
}

// ---------------------------------------------------------------------------
// 2) QKV GEMM  qkv[2048 x 6144] = x * [wq|wk|wv]^T.
//    r17: 2-BARRIER-PER-TILE schedule (was 8). BM=256, BN=192, BK=64,
//    grid (32,8) = 256 blocks, 8 waves 4M x 2N (per-wave 64x96).
//    ph0: readA(h0+h1)+readB(h0); stage A-h0,A-h1,B-h0(t+1); mma 48 (n-half0);
//         WAITV(6) [lands B-h1(t)]; BAR.
//    ph1: readB(h1); stage B-h1(t+1); mma 48 (n-half1);
//         WAITV(2) [lands A,B-h0(t+1)]; BAR.
//    Hazard proof: stage into buf^1 region R at tile t; R's readers ran at
//    tile t-1 and were consumed by t-1's mma, which precedes >=1 barrier
//    before t's stage. MFMA order per acc element unchanged vs r12 ->
//    bit-identical output.
// ---------------------------------------------------------------------------
__global__ __launch_bounds__(512) void gemm_qkv(
    const unsigned short* __restrict__ A,    // xb  [2048 x 4096]
    const unsigned short* __restrict__ B0,   // wq  [4096 x 4096]
    const unsigned short* __restrict__ B1,   // wk  [1024 x 4096]
    const unsigned short* __restrict__ B2,   // wv  [1024 x 4096]
    unsigned short* __restrict__ C)          // qkv [2048 x 6144]
{
    constexpr int K = 4096, BK = 64, NT = K / BK;
    __shared__ unsigned short As[2][256 * 64];   // 64 KB
    __shared__ unsigned short Bs[2][192 * 64];   // 48 KB

    const int bm = blockIdx.y, bn = blockIdx.x;  // (32, 8): lin%8 == bn%8
    const int tid = threadIdx.x;
    const int w = tid >> 6, lane = tid & 63;
    const int wr = w >> 1, wc = w & 1;           // 4M x 2N
    const int r16 = lane & 15, g4 = lane >> 4;

    const int bn0 = bn * 192;
    const unsigned short* Ap = A + (size_t)bm * 256 * K;

    const int lrow = lane >> 3;   // 0..7 (row within 8-row unit)
    const int lchk = lane & 7;    // 0..7 (16B chunk within 128B row)

    f32x4 acc[4][6] = {};
    bf16x8 af[4][2], b0[3][2], b1[3][2];

    auto browbase = [&](int rowg) -> const unsigned short* {
        if (rowg < 4096) return B0 + (size_t)rowg * K;
        if (rowg < 5120) return B1 + (size_t)(rowg - 4096) * K;
        return B2 + (size_t)(rowg - 5120) * K;
    };

    auto stageA = [&](int buf, int tt, int half) {
        #pragma unroll
        for (int i = 0; i < 2; ++i) {
            const int j = i * 8 + w;                               // unit 0..15
            const int row0 = (j >> 2) * 64 + half * 32 + (j & 3) * 8;
            const int row = row0 + lrow;
            gload_lds16(Ap + (size_t)row * K + tt * BK + ((lchk ^ (row & 7)) * 8),
                        &As[buf][row0 * 64]);
        }
    };
    auto stageB = [&](int buf, int tt, int half) {
        #pragma unroll
        for (int i = 0; i < 2; ++i) {
            const int j = (i == 0) ? w : (8 + (w & 3));            // unit 0..11
            const int row0 = (j < 6) ? (half * 48 + j * 8)
                                     : (96 + half * 48 + (j - 6) * 8);
            const int row = row0 + lrow;
            const unsigned short* src = browbase(bn0 + row0) + (size_t)lrow * K;
            gload_lds16(src + tt * BK + ((lchk ^ (row & 7)) * 8),
                        &Bs[buf][row0 * 64]);
        }
    };
    auto readA = [&](int buf, int mh) {
        #pragma unroll
        for (int m = 0; m < 2; ++m)
            #pragma unroll
            for (int kk = 0; kk < 2; ++kk) {
                const int row = wr * 64 + mh * 32 + m * 16 + r16;
                af[mh * 2 + m][kk] = *reinterpret_cast<const bf16x8*>(
                    &As[buf][row * 64 + (((kk * 4 + g4) ^ (row & 7)) * 8)]);
            }
    };
    auto readB = [&](int buf, int nh, bf16x8 (&br)[3][2]) {
        #pragma unroll
        for (int n = 0; n < 3; ++n)
            #pragma unroll
            for (int kk = 0; kk < 2; ++kk) {
                const int row = wc * 96 + nh * 48 + n * 16 + r16;
                br[n][kk] = *reinterpret_cast<const bf16x8*>(
                    &Bs[buf][row * 64 + (((kk * 4 + g4) ^ (row & 7)) * 8)]);
            }
    };
    auto mma = [&](bf16x8 (&br)[3][2], int nh) {   // all 4 m-frags x 3 n-frags
        __builtin_amdgcn_s_setprio(1);
        #pragma unroll
        for (int m = 0; m < 4; ++m)
            #pragma unroll
            for (int n = 0; n < 3; ++n)
                #pragma unroll
                for (int kk = 0; kk < 2; ++kk)
                    acc[m][nh * 3 + n] = __builtin_amdgcn_mfma_f32_16x16x32_bf16(
                        af[m][kk], br[n][kk], acc[m][nh * 3 + n], 0, 0, 0);
        __builtin_amdgcn_s_setprio(0);
    };

    // prologue: stage tile 0 fully, drain
    stageA(0, 0, 0); stageA(0, 0, 1); stageB(0, 0, 0); stageB(0, 0, 1);
    waitv<0>();
    BAR();

    for (int t = 0; t < NT - 1; ++t) {
        const int buf = t & 1;
        // ---- phase 0: all-m x n-half0 ----
        readA(buf, 0); readA(buf, 1); readB(buf, 0, b0);
        stageA(buf ^ 1, t + 1, 0); stageA(buf ^ 1, t + 1, 1); stageB(buf ^ 1, t + 1, 0);
        mma(b0, 0);
        waitv<6>();                 // lands B-h1(t); leaves A0',A1',B0'(t+1)
        BAR();
        // ---- phase 1: all-m x n-half1 ----
        readB(buf, 1, b1);
        stageB(buf ^ 1, t + 1, 1);
        mma(b1, 1);
        waitv<2>();                 // lands A0',A1',B0'(t+1); leaves B1'(t+1)
        BAR();
    }
    // ---- last tile (no staging) ----
    {
        const int buf = (NT - 1) & 1;
        readA(buf, 0); readA(buf, 1); readB(buf, 0, b0);
        mma(b0, 0);
        waitv<0>();                 // B-h1 landed (was left in flight)
        BAR();
        readB(buf, 1, b1);
        mma(b1, 1);
    }

    // ---- epilogue ----
    const size_t crow0 = (size_t)bm * 256 + wr * 64;
    const size_t ccol0 = (size_t)bn0 + wc * 96;
    #pragma unroll
    for (int m = 0; m < 4; ++m)
        #pragma unroll
        for (int n = 0; n < 6; ++n)
            #pragma unroll
            for (int r = 0; r < 4; ++r)
                C[(crow0 + m * 16 + g4 * 4 + r) * QKVW + ccol0 + n * 16 + r16] =
                    f2b(acc[m][n][r]);
}

// ---------------------------------------------------------------------------
// 2b) O-proj GEMM  out[2048 x 4096] = ob * wo^T.
//     r17: 2-barrier-per-tile (was 8). BM=128, BN=256, BK=64,
//     grid (16,16) = 256 blocks, 8 waves 2M x 4N (per-wave 64x64).
//     Loads/tile: A-h0(1)+A-h1(1)+B-h0(2) at ph0, B-h1(2) at ph1 -> 6.
//     ph0 WAITV(4) [lands B-h1(t)]; ph1 WAITV(2) [lands A,B-h0(t+1)].
// ---------------------------------------------------------------------------
__global__ __launch_bounds__(512) void gemm_out(
    const unsigned short* __restrict__ A,   // ob  [2048 x 4096] bf16
    const unsigned short* __restrict__ B,   // wob [4096 x 4096] bf16
    float* __restrict__ C)                  // out [2048 x 4096] f32
{
    constexpr int K = 4096, BK = 64, NT = K / BK;
    __shared__ unsigned short As[2][128 * 64];   // 32 KB
    __shared__ unsigned short Bs[2][256 * 64];   // 64 KB

    const int bm = blockIdx.y, bn = blockIdx.x;  // (16, 16): lin%8 == bn%8
    const int tid = threadIdx.x;
    const int w = tid >> 6, lane = tid & 63;
    const int wr = w >> 2, wc = w & 3;           // 2M x 4N
    const int r16 = lane & 15, g4 = lane >> 4;

    const unsigned short* Ap = A + (size_t)bm * 128 * K;
    const unsigned short* Bp = B + (size_t)bn * 256 * K;

    const int lrow = lane >> 3;
    const int lchk = lane & 7;

    f32x4 acc[4][4] = {};
    bf16x8 af[4][2], b0[2][2], b1[2][2];

    auto stageA = [&](int buf, int tt, int half) {
        const int j = w;                                           // unit 0..7
        const int row0 = (j >> 2) * 64 + half * 32 + (j & 3) * 8;
        const int row = row0 + lrow;
        gload_lds16(Ap + (size_t)row * K + tt * BK + ((lchk ^ (row & 7)) * 8),
                    &As[buf][row0 * 64]);
    };
    auto stageB = [&](int buf, int tt, int half) {
        #pragma unroll
        for (int i = 0; i < 2; ++i) {
            const int j = i * 8 + w;                               // unit 0..15
            const int row0 = (j >> 2) * 64 + half * 32 + (j & 3) * 8;
            const int row = row0 + lrow;
            gload_lds16(Bp + (size_t)row * K + tt * BK + ((lchk ^ (row & 7)) * 8),
                        &Bs[buf][row0 * 64]);
        }
    };
    auto readA = [&](int buf, int mh) {
        #pragma unroll
        for (int m = 0; m < 2; ++m)
            #pragma unroll
            for (int kk = 0; kk < 2; ++kk) {
                const int row = wr * 64 + mh * 32 + m * 16 + r16;
                af[mh * 2 + m][kk] = *reinterpret_cast<const bf16x8*>(
                    &As[buf][row * 64 + (((kk * 4 + g4) ^ (row & 7)) * 8)]);
            }
    };
    auto readB = [&](int buf, int nh, bf16x8 (&br)[2][2]) {
        #pragma unroll
        for (int n = 0; n < 2; ++n)
            #pragma unroll
            for (int kk = 0; kk < 2; ++kk) {
                const int row = wc * 64 + nh * 32 + n * 16 + r16;
                br[n][kk] = *reinterpret_cast<const bf16x8*>(
                    &Bs[buf][row * 64 + (((kk * 4 + g4) ^ (row & 7)) * 8)]);
            }
    };
    auto mma = [&](bf16x8 (&br)[2][2], int nh) {   // all 4 m-frags x 2 n-frags
        __builtin_amdgcn_s_setprio(1);
        #pragma unroll
        for (int m = 0; m < 4; ++m)
            #pragma unroll
            for (int n = 0; n < 2; ++n)
                #pragma unroll
                for (int kk = 0; kk < 2; ++kk)
                    acc[m][nh * 2 + n] = __builtin_amdgcn_mfma_f32_16x16x32_bf16(
                        af[m][kk], br[n][kk], acc[m][nh * 2 + n], 0, 0, 0);
        __builtin_amdgcn_s_setprio(0);
    };

    stageA(0, 0, 0); stageA(0, 0, 1); stageB(0, 0, 0); stageB(0, 0, 1);
    waitv<0>();
    BAR();

    for (int t = 0; t < NT - 1; ++t) {
        const int buf = t & 1;
        // ---- phase 0 ----
        readA(buf, 0); readA(buf, 1); readB(buf, 0, b0);
        stageA(buf ^ 1, t + 1, 0); stageA(buf ^ 1, t + 1, 1); stageB(buf ^ 1, t + 1, 0);
        mma(b0, 0);
        waitv<4>();                 // lands B-h1(t); leaves A0',A1',B0'(t+1)
        BAR();
        // ---- phase 1 ----
        readB(buf, 1, b1);
        stageB(buf ^ 1, t + 1, 1);
        mma(b1, 1);
        waitv<2>();                 // lands A0',A1',B0'(t+1); leaves B1'(t+1)
        BAR();
    }
    {
        const int buf = (NT - 1) & 1;
        readA(buf, 0); readA(buf, 1); readB(buf, 0, b0);
        mma(b0, 0);
        waitv<0>();
        BAR();
        readB(buf, 1, b1);
        mma(b1, 1);
    }

    const size_t crow0 = (size_t)bm * 128 + wr * 64;
    const size_t ccol0 = (size_t)bn * 256 + wc * 64;
    #pragma unroll
    for (int m = 0; m < 4; ++m)
        #pragma unroll
        for (int n = 0; n < 4; ++n)
            #pragma unroll
            for (int r = 0; r < 4; ++r)
                C[(crow0 + m * 16 + g4 * 4 + r) * DD + ccol0 + n * 16 + r16] = acc[m][n][r];
}

// ---------------------------------------------------------------------------
// 3+4) Merged RoPE + V-transpose (unchanged from r16).
// ---------------------------------------------------------------------------
__global__ __launch_bounds__(256) void rope_tv(unsigned short* __restrict__ qkv,
                                               const float* __restrict__ fc,
                                               const float* __restrict__ fs,
                                               unsigned short* __restrict__ Vt) {
    __shared__ unsigned short tile[64][72];
    const int bid = blockIdx.x;
    if (bid < 6144) {
        constexpr float QSCALE = 0.08838834764831845f * 1.4426950408889634f;
        const int g = (bid % 3) * 256 + threadIdx.x;   // 0..767, groups of 8 cols
        if (g >= 640) return;
        const int s = bid / 3;
        const int col = g * 8;
        unsigned short* p = qkv + (size_t)s * QKVW + col;
        u16x8 v = *reinterpret_cast<const u16x8*>(p);
        const int i0 = (col & 127) >> 1;
        f32x4 c  = *reinterpret_cast<const f32x4*>(fc + s * 64 + i0);
        f32x4 sn = *reinterpret_cast<const f32x4*>(fs + s * 64 + i0);
        const float post = (col < DD) ? QSCALE : 1.0f;
        u16x8 o;
        #pragma unroll
        for (int j = 0; j < 4; ++j) {
            float e  = b2f(v[2*j]);
            float od = b2f(v[2*j+1]);
            o[2*j]   = f2b((e * c[j] - od * sn[j]) * post);
            o[2*j+1] = f2b((e * sn[j] + od * c[j]) * post);
        }
        *reinterpret_cast<u16x8*>(p) = o;
    } else {
        const int t = bid - 6144;                      // 0..511
        const int d0g = (t & 15) * 64;
        const int s0  = (t >> 4) * 64;
        const int kvh = d0g >> 7, dl0 = d0g & 127;
        const int tid = threadIdx.x;
        #pragma unroll
        for (int p = 0; p < 2; ++p) {
            const int sgi = p * 256 + tid;
            const int srow = sgi >> 3, dseg = sgi & 7;
            u16x8 v = *reinterpret_cast<const u16x8*>(
                qkv + (size_t)(s0 + srow) * QKVW + 5120 + d0g + dseg * 8);
            #pragma unroll
            for (int j = 0; j < 8; ++j) tile[srow][dseg * 8 + j] = v[j];
        }
        __syncthreads();
        #pragma unroll
        for (int p = 0; p < 2; ++p) {
            const int sgi = p * 256 + tid;
            const int drow = sgi >> 3, sseg = sgi & 7;
            u16x8 v;
            #pragma unroll
            for (int j = 0; j < 8; ++j) v[j] = tile[sseg * 8 + j][drow];
            *reinterpret_cast<u16x8*>(
                Vt + (size_t)kvh * HD2 * S2 + (size_t)(dl0 + drow) * S2 + s0 + sseg * 8) = v;
        }
    }
}

// ---------------------------------------------------------------------------
// 5) Flash attention (r16: r12 body + thin-spread wo conversion side-job).
// ---------------------------------------------------------------------------
__global__ __launch_bounds__(512) void attn_kernel(const unsigned short* __restrict__ Qkv,
                                                   const unsigned short* __restrict__ Vt,
                                                   unsigned short* __restrict__ O,
                                                   const float* __restrict__ wo_src,
                                                   unsigned short* __restrict__ wo_dst) {
    __shared__ unsigned short Klds[2][64 * 128];   // 32 KB
    __shared__ unsigned short Vlds[2][128 * 64];   // 32 KB
    __shared__ unsigned short Plds[8][2048];       // 32 KB (4 KB/wave, frag-ordered)

    const int kvh = blockIdx.x;                  // 0..7
    const int h   = kvh * 4 + (blockIdx.y & 3);
    const int p   = blockIdx.y >> 2;             // pair id 0..7
    const int cB  = 8 + p, cS = 7 - p;           // complement chunks
    const int w = threadIdx.x >> 6, lane = threadIdx.x & 63;
    const int tid = threadIdx.x;
    const int r16 = lane & 15, g4 = lane >> 4;

    const int myc = (w < 4) ? cB : cS;
    const int qw  = myc * 128 + (w & 3) * 32;    // wave's first q row
    const int ntB = 2 * cB + 2;                  // tiles staged by this block (>= 18)

    const unsigned short* Kbase = Qkv + DD + kvh * HD2;      // + kv*QKVW + d
    const unsigned short* Vtb   = Vt + (size_t)kvh * HD2 * S2;
    char* pw = (char*)(&Plds[w][0]);             // wave's 4KB P region

    // wo conversion side-job: block blk covers 16384 f32x4 groups,
    // 16 batches x (2 f32x4 per thread), issue at tile k, flush at k+1.
    const int blk = blockIdx.y * 8 + blockIdx.x;           // 0..255
    const f32x4* wo4 = (const f32x4*)wo_src;
    const int cb4 = blk * 16384 + tid;
    f32x4 cbuf[2];
    auto cvt_issue = [&](int k) {
        #pragma unroll
        for (int i = 0; i < 2; ++i)
            cbuf[i] = wo4[cb4 + k * 1024 + i * 512];
    };
    auto cvt_flush = [&](int k) {
        #pragma unroll
        for (int i = 0; i < 2; ++i) {
            u16x4 ov;
            ov[0] = f2b(cbuf[i][0]); ov[1] = f2b(cbuf[i][1]);
            ov[2] = f2b(cbuf[i][2]); ov[3] = f2b(cbuf[i][3]);
            *reinterpret_cast<u16x4*>(wo_dst + ((size_t)(cb4 + k * 1024 + i * 512)) * 4) = ov;
        }
    };

    // staging lane constants
    const int krow_l = lane >> 4;      // row within 4-row segment
    const int kchunk = lane & 15;      // 16B chunk within 256B K row
    const int vd_l   = lane >> 3;      // d within 8-row segment
    const int vchunk = lane & 7;       // 16B chunk within 128B V row

    // Q fragments (B-frag of swapped QK^T): rows qw+m*16+r16, d-slices f*32+g4*8
    bf16x8 qf[2][4];
    #pragma unroll
    for (int m = 0; m < 2; ++m)
        #pragma unroll
        for (int f = 0; f < 4; ++f)
            qf[m][f] = *reinterpret_cast<const bf16x8*>(
                Qkv + (size_t)(qw + m * 16 + r16) * QKVW + h * HD2 + f * 32 + g4 * 8);

    f32x4 o[2][8] = {};
    float mr[2] = {-3e38f, -3e38f};   // running max (log2 units) for q = m*16+r16
    float lr[2] = {0.f, 0.f};

    auto stage = [&](int buf, int kv0) {
        #pragma unroll
        for (int i = 0; i < 2; ++i) {
            const int seg = i * 8 + w;                     // 0..15
            const int row = seg * 4 + krow_l;              // kv row 0..63
            gload_lds16(Kbase + (size_t)(kv0 + row) * QKVW + ((kchunk ^ (row & 7)) * 8),
                        &Klds[buf][seg * 512]);
        }
        #pragma unroll
        for (int i = 0; i < 2; ++i) {
            const int seg = i * 8 + w;
            const int d = seg * 8 + vd_l;                  // d row 0..127
            gload_lds16(Vtb + (size_t)d * S2 + kv0 + ((vchunk ^ (d & 7)) * 8),
                        &Vlds[buf][seg * 512]);
        }
    };

    stage(0, 0);
    WAITV(0);
    __syncthreads();
    cvt_issue(0);                                 // overlaps tile 0 compute

    for (int t = 0; t < ntB; ++t) {
        if (t >= 1 && t <= 16) {                  // batch t-1 drained at tile t-1 end
            cvt_flush(t - 1);
            if (t < 16) cvt_issue(t);
        }
        const int buf = t & 1;
        const int kv0 = t * 64;
        if (t + 1 < ntB) stage(buf ^ 1, (t + 1) * 64);

        if (kv0 <= qw + 31) {                 // causal: this wave needs the tile
            // ---- QK^T swapped: sa[m][kb] = K_tile * Q^T -> C[kv][q] ----
            f32x4 sa[2][4] = {};
            #pragma unroll
            for (int kb = 0; kb < 4; ++kb) {
                bf16x8 kf[4];
                #pragma unroll
                for (int f = 0; f < 4; ++f)
                    kf[f] = *reinterpret_cast<const bf16x8*>(
                        &Klds[buf][(kb * 16 + r16) * 128 + (((f * 4 + g4) ^ (r16 & 7)) * 8)]);
                __builtin_amdgcn_s_setprio(1);
                #pragma unroll
                for (int m = 0; m < 2; ++m)
                    #pragma unroll
                    for (int f = 0; f < 4; ++f)
                        sa[m][kb] = __builtin_amdgcn_mfma_f32_16x16x32_bf16(
                            kf[f], qf[m][f], sa[m][kb], 0, 0, 0);
                __builtin_amdgcn_s_setprio(0);
            }
            // ---- causal mask: lane holds q = qw+m*16+r16, kv = kv0+kb*16+g4*4+r ----
            const bool needmask = (kv0 + 63 > qw);
            float sv[2][4][4];
            #pragma unroll
            for (int m = 0; m < 2; ++m)
                #pragma unroll
                for (int kb = 0; kb < 4; ++kb)
                    #pragma unroll
                    for (int r = 0; r < 4; ++r) {
                        float xx = sa[m][kb][r];
                        if (needmask) {
                            const int kvg = kv0 + kb * 16 + g4 * 4 + r;
                            const int qg  = qw + m * 16 + r16;
                            xx = (kvg > qg) ? -3e38f : xx;
                        }
                        sv[m][kb][r] = xx;
                    }
            // ---- per-q max: 15 in-lane ops + 2 shfl levels ----
            float rowm[2];
            #pragma unroll
            for (int m = 0; m < 2; ++m) {
                float a0 = fmaxf(fmaxf(sv[m][0][0], sv[m][0][1]), fmaxf(sv[m][0][2], sv[m][0][3]));
                float a1 = fmaxf(fmaxf(sv[m][1][0], sv[m][1][1]), fmaxf(sv[m][1][2], sv[m][1][3]));
                float a2 = fmaxf(fmaxf(sv[m][2][0], sv[m][2][1]), fmaxf(sv[m][2][2], sv[m][2][3]));
                float a3 = fmaxf(fmaxf(sv[m][3][0], sv[m][3][1]), fmaxf(sv[m][3][2], sv[m][3][3]));
                rowm[m] = fmaxf(fmaxf(a0, a1), fmaxf(a2, a3));
            }
            #pragma unroll
            for (int m = 0; m < 2; ++m) {
                rowm[m] = fmaxf(rowm[m], __shfl_xor(rowm[m], 16));
                rowm[m] = fmaxf(rowm[m], __shfl_xor(rowm[m], 32));
            }
            // ---- defer-max (T13, base-2 THR = 11.5 ~ e^8) ----
            const float gmax = fmaxf(rowm[0] - mr[0], rowm[1] - mr[1]);
            if (!__all(gmax <= 11.5f)) {
                float corr[2];
                #pragma unroll
                for (int m = 0; m < 2; ++m) {
                    const float mn = fmaxf(mr[m], rowm[m]);
                    corr[m] = exp2f(mr[m] - mn);
                    mr[m] = mn;
                    lr[m] *= corr[m];
                }
                #pragma unroll
                for (int m = 0; m < 2; ++m)
                    #pragma unroll
                    for (int r = 0; r < 4; ++r) {
                        const float co = __shfl(corr[m], (lane & 48) | (g4 * 4 + r));
                        #pragma unroll
                        for (int n = 0; n < 8; ++n) o[m][n][r] *= co;
                    }
            }
            // ---- P = exp2(S - m), row sums (in-lane + 2 shfl) ----
            float rs[2] = {0.f, 0.f};
            #pragma unroll
            for (int m = 0; m < 2; ++m)
                #pragma unroll
                for (int kb = 0; kb < 4; ++kb)
                    #pragma unroll
                    for (int r = 0; r < 4; ++r) {
                        const float pp = exp2f(sv[m][kb][r] - mr[m]);
                        sv[m][kb][r] = pp;
                        rs[m] += pp;
                    }
            #pragma unroll
            for (int m = 0; m < 2; ++m) {
                rs[m] += __shfl_xor(rs[m], 16);
                rs[m] += __shfl_xor(rs[m], 32);
                lr[m] += rs[m];
            }
            // ---- pack P pairs (cvt_pk) -> fragment-ordered Plds, 8 b64 writes ----
            #pragma unroll
            for (int m = 0; m < 2; ++m)
                #pragma unroll
                for (int kb = 0; kb < 4; ++kb) {
                    const unsigned w0 = cvt_pk_bf16(sv[m][kb][0], sv[m][kb][1]);
                    const unsigned w1 = cvt_pk_bf16(sv[m][kb][2], sv[m][kb][3]);
                    int wa = m * 2048 + ((kb * 2) + (g4 >> 1)) * 256 + r16 * 16 + (g4 & 1) * 8;
                    wa ^= (r16 >> 3) << 4;
                    *reinterpret_cast<unsigned long long*>(pw + wa) =
                        (unsigned long long)w0 | ((unsigned long long)w1 << 32);
                }
            asm volatile("s_waitcnt lgkmcnt(0)" ::: "memory");
            bf16x8 pa[2][2];
            #pragma unroll
            for (int m = 0; m < 2; ++m)
                #pragma unroll
                for (int kvs = 0; kvs < 2; ++kvs) {
                    int ra = m * 2048 + kvs * 1024 + lane * 16;
                    ra ^= (r16 >> 3) << 4;
                    pa[m][kvs] = *reinterpret_cast<const bf16x8*>(pw + ra);
                }
            // ---- PV: O[q][d] += P[q][kv] * Vt[d][kv] ----
            #pragma unroll
            for (int kvs = 0; kvs < 2; ++kvs)
                #pragma unroll
                for (int n = 0; n < 8; ++n) {
                    const bf16x8 vb = *reinterpret_cast<const bf16x8*>(
                        &Vlds[buf][(n * 16 + r16) * 64 + (((kvs * 4 + g4) ^ (r16 & 7)) * 8)]);
                    __builtin_amdgcn_s_setprio(1);
                    #pragma unroll
                    for (int m = 0; m < 2; ++m)
                        o[m][n] = __builtin_amdgcn_mfma_f32_16x16x32_bf16(
                            pa[m][kvs], vb, o[m][n], 0, 0, 0);
                    __builtin_amdgcn_s_setprio(0);
                }
        }

        WAITV(0);
        __syncthreads();
    }

    // ---- normalize (broadcast 1/lr to o-layout lanes) + write ----
    float inv[2];
    #pragma unroll
    for (int m = 0; m < 2; ++m) inv[m] = 1.0f / lr[m];
    #pragma unroll
    for (int m = 0; m < 2; ++m)
        #pragma unroll
        for (int r = 0; r < 4; ++r) {
            const float iv = __shfl(inv[m], (lane & 48) | (g4 * 4 + r));
            #pragma unroll
            for (int n = 0; n < 8; ++n)
                O[(size_t)(qw + m * 16 + g4 * 4 + r) * DD + h * HD2 + n * 16 + r16] =
                    f2b(o[m][n][r] * iv);
        }
}

// ---------------------------------------------------------------------------
extern "C" void kernel_launch(void* const* d_in, const int* in_sizes, int n_in,
                              void* d_out, int out_size, void* d_ws, size_t ws_size,
                              hipStream_t stream) {
    (void)in_sizes; (void)n_in; (void)out_size; (void)ws_size;
    const float* x  = (const float*)d_in[0];
    const float* wq = (const float*)d_in[1];
    const float* wk = (const float*)d_in[2];
    const float* wv = (const float*)d_in[3];
    const float* wo = (const float*)d_in[4];
    // d_in[5] = mask (causal tril; computed analytically in-kernel)
    const float* fc = (const float*)d_in[6];
    const float* fs = (const float*)d_in[7];
    float* out = (float*)d_out;

    unsigned short* ws = (unsigned short*)d_ws;
    const size_t M1 = 1024 * 1024;
    unsigned short* xb  = ws;              // 8M  (x bf16)
    unsigned short* wqb = ws + 8  * M1;    // 16M
    unsigned short* wkb = ws + 24 * M1;    // 4M
    unsigned short* wvb = ws + 28 * M1;    // 4M
    unsigned short* wob = ws + 32 * M1;    // 16M (written by attn side-job)
    unsigned short* qkv = ws + 48 * M1;    // 12M (S x 6144)
    unsigned short* vt  = ws + 60 * M1;    // 2M  (KVH x 128 x S)
    unsigned short* ob  = ws + 62 * M1;    // 8M  (S x 4096)

    cvt_all<<<2048, 256, 0, stream>>>(x, wq, wk, wv, ws);
    gemm_qkv<<<dim3(32, 8), 512, 0, stream>>>(xb, wqb, wkb, wvb, qkv);
    rope_tv<<<6656, 256, 0, stream>>>(qkv, fc, fs, vt);
    attn_kernel<<<dim3(8, 32), 512, 0, stream>>>(qkv, vt, ob, wo, wob);
    gemm_out<<<dim3(16, 16), 512, 0, stream>>>(ob, wob, out);
}